// Round 15
// baseline (343.399 us; speedup 1.0000x reference)
//
#include <hip/hip_runtime.h>
#include <cmath>

typedef __attribute__((ext_vector_type(8))) short short8;
typedef __attribute__((ext_vector_type(4))) float floatx4;

#define TT 2048
#define CCH 512
#define MROWS 8192
static const size_t N1 = 4194304;   // 8192*512 elements
#define LOG2E 1.44269504088896340736f

__device__ __forceinline__ float gelu_f(float x) {
    return 0.5f * x * (1.0f + erff(x * 0.70710678118654752440f));
}
__device__ __forceinline__ unsigned short f2bf(float x) {
    union { float f; unsigned u; } v; v.f = x;
    unsigned r = v.u + 0x7fffu + ((v.u >> 16) & 1u);
    return (unsigned short)(r >> 16);
}
__device__ __forceinline__ float bf2f(unsigned short h) {
    union { unsigned u; float f; } v; v.u = ((unsigned)h) << 16;
    return v.f;
}
__device__ __forceinline__ unsigned cvtpk(float a, float b) {
    unsigned r;
    asm("v_cvt_pk_bf16_f32 %0, %1, %2" : "=v"(r) : "v"(a), "v"(b));
    return r;
}
__device__ __forceinline__ void gld16(const unsigned short* g, unsigned short* l) {
    __builtin_amdgcn_global_load_lds(
        (const __attribute__((address_space(1))) void*)g,
        (__attribute__((address_space(3))) void*)l, 16, 0, 0);
}

// ---------------- weight pack: fp32 -> bf16 (conv weights re-laid-out) ----------------
__global__ __launch_bounds__(256)
void pack_w(const float* __restrict__ qkvw, const float* __restrict__ outw,
            const float* __restrict__ w1, const float* __restrict__ w2,
            const float* __restrict__ pw, const float* __restrict__ cv,
            unsigned short* __restrict__ W)
{
    const int idx = blockIdx.x * 256 + threadIdx.x;
    float v;
    if (idx < 786432)            v = qkvw[idx];
    else if (idx < 1048576)      v = outw[idx - 786432];
    else if (idx < 2097152)      v = w1[idx - 1048576];
    else if (idx < 3145728)      v = w2[idx - 2097152];
    else if (idx < 3407872)      v = pw[idx - 3145728];
    else {
        const int l = idx - 3407872;
        const int n = l / 1536, k = l - n * 1536;
        const int ks = k >> 9, ci = k & 511;
        v = cv[n * 1536 + ci * 3 + ks];
    }
    W[idx] = f2bf(v);
}

// ---------------- fused: xpad bf16 (zero-padded rows) + DSA LayerNorm ----------------
__global__ __launch_bounds__(256)
void pack_x(const float* __restrict__ x, const float* __restrict__ gam,
            const float* __restrict__ bet, unsigned short* __restrict__ z,
            unsigned short* __restrict__ xpad)
{
    const int m = blockIdx.x, tid = threadIdx.x;
    const int b = m >> 11, t = m & (TT - 1);
    const float2 xv = *(const float2*)&x[(size_t)m * 512 + 2 * tid];
    float s = xv.x + xv.y, sq = xv.x * xv.x + xv.y * xv.y;
    #pragma unroll
    for (int off = 32; off; off >>= 1) { s += __shfl_xor(s, off); sq += __shfl_xor(sq, off); }
    __shared__ float ws[4], wq[4];
    const int wave = tid >> 6, lane = tid & 63;
    if (lane == 0) { ws[wave] = s; wq[wave] = sq; }
    __syncthreads();
    s = ws[0] + ws[1] + ws[2] + ws[3];
    sq = wq[0] + wq[1] + wq[2] + wq[3];
    const float mean = s * (1.0f / 512.0f);
    const float var = sq * (1.0f / 512.0f) - mean * mean;
    const float rstd = rsqrtf(var + 1e-5f);
    const float y0 = (xv.x - mean) * rstd * gam[2 * tid]     + bet[2 * tid];
    const float y1 = (xv.y - mean) * rstd * gam[2 * tid + 1] + bet[2 * tid + 1];
    *(unsigned*)&z[(size_t)m * 512 + 2 * tid] = ((unsigned)f2bf(y1) << 16) | f2bf(y0);
    *(unsigned*)&xpad[((size_t)(b * (TT + 2) + t + 1)) * 512 + 2 * tid] =
        ((unsigned)f2bf(xv.y) << 16) | f2bf(xv.x);
    if (t == 0)
        *(unsigned*)&xpad[((size_t)(b * (TT + 2))) * 512 + 2 * tid] = 0u;
    if (t == TT - 1)
        *(unsigned*)&xpad[((size_t)(b * (TT + 2) + TT + 1)) * 512 + 2 * tid] = 0u;
}

// ---------------- LayerNorm rows of 512, bf16 -> bf16 ----------------
__global__ __launch_bounds__(256)
void ln_bf(const unsigned short* __restrict__ in, const float* __restrict__ gam,
           const float* __restrict__ bet, unsigned short* __restrict__ out)
{
    const int m = blockIdx.x, tid = threadIdx.x;
    const unsigned pv = *(const unsigned*)&in[(size_t)m * 512 + 2 * tid];
    const float x0 = bf2f((unsigned short)pv), x1 = bf2f((unsigned short)(pv >> 16));
    float s = x0 + x1, sq = x0 * x0 + x1 * x1;
    #pragma unroll
    for (int off = 32; off; off >>= 1) { s += __shfl_xor(s, off); sq += __shfl_xor(sq, off); }
    __shared__ float ws[4], wq[4];
    const int wave = tid >> 6, lane = tid & 63;
    if (lane == 0) { ws[wave] = s; wq[wave] = sq; }
    __syncthreads();
    s = ws[0] + ws[1] + ws[2] + ws[3];
    sq = wq[0] + wq[1] + wq[2] + wq[3];
    const float mean = s * (1.0f / 512.0f);
    const float var = sq * (1.0f / 512.0f) - mean * mean;
    const float rstd = rsqrtf(var + 1e-5f);
    const float y0 = (x0 - mean) * rstd * gam[2 * tid]     + bet[2 * tid];
    const float y1 = (x1 - mean) * rstd * gam[2 * tid + 1] + bet[2 * tid + 1];
    *(unsigned*)&out[(size_t)m * 512 + 2 * tid] = ((unsigned)f2bf(y1) << 16) | f2bf(y0);
}

// ---------------- depthwise conv k=3 + bias + gelu ----------------
__global__ __launch_bounds__(256)
void dwconv_k(const unsigned short* __restrict__ z, const float* __restrict__ dw,
              const float* __restrict__ db, unsigned short* __restrict__ g)
{
    const int m = blockIdx.x, tid = threadIdx.x, t = m & (TT - 1);
    const int c = 2 * tid;
    const size_t base = (size_t)m * 512 + c;
    const unsigned vm = *(const unsigned*)&z[base];
    const unsigned va = (t > 0)      ? *(const unsigned*)&z[base - 512] : 0u;
    const unsigned vc = (t < TT - 1) ? *(const unsigned*)&z[base + 512] : 0u;
    float y[2];
    #pragma unroll
    for (int j = 0; j < 2; ++j) {
        const float a  = bf2f((unsigned short)(va >> (16 * j)));
        const float bb = bf2f((unsigned short)(vm >> (16 * j)));
        const float cc = bf2f((unsigned short)(vc >> (16 * j)));
        const int ch = c + j;
        y[j] = gelu_f(a * dw[ch * 3] + bb * dw[ch * 3 + 1] + cc * dw[ch * 3 + 2] + db[ch]);
    }
    *(unsigned*)&g[base] = ((unsigned)f2bf(y[1]) << 16) | f2bf(y[0]);
}

// --- bf16 MFMA GEMM body: TM=64/TN=128, NBUF=2, 24 KB LDS (6 blocks/CU),
//     simple 2-buffer loop, bijective XCD-chunked block swizzle.
// EPI: 0=qkv-split  1=bias->bf16  2=gelu+res(f32)->bf16  3=bias+res(f32)->bf16
//      4=bias+gelu->bf16  5=final combine -> f32
// AF : 0=A plain bf16 row-major   1=A from xpad (conv premix im2col)
template<int EPI, int AF>
__device__ __forceinline__ void gemm_body(
    const unsigned short* __restrict__ A, const unsigned short* __restrict__ Bw,
    const float* __restrict__ bias, const float* __restrict__ resf,
    const unsigned short* __restrict__ dsa,
    const float* __restrict__ sA, const float* __restrict__ sB,
    float* __restrict__ outf, unsigned short* __restrict__ o1,
    unsigned short* __restrict__ o2, unsigned short* __restrict__ o3,
    int Nn, int K, int gx, unsigned short* AsB, unsigned short* BsB)
{
    constexpr int MI = 4, NJ = 2;
    constexpr int ASTR = 64 * 32, BSTR = 128 * 32;

    const int nwg = gx * gridDim.y;
    const int orig = blockIdx.x + gx * blockIdx.y;
    const int wg = (orig & 7) * (nwg >> 3) + (orig >> 3);
    const int bx = wg % gx, by = wg / gx;

    const int tid = threadIdx.x;
    const int bm = by * 64, bn = bx * 128;
    const int lane = tid & 63, w = tid >> 6;
    const int wc = w;
    const int lr = lane & 15, g = lane >> 4;

    auto stage = [&](int buf, int k0) {
        unsigned short* Asb = AsB + buf * ASTR;
        unsigned short* Bsb = BsB + buf * BSTR;
        {
            const int c = tid;
            const int r = c >> 2, c8 = c & 3;
            const int c8s = c8 ^ ((r >> 1) & 3);
            const unsigned short* src;
            if (AF == 1) {
                const int m = bm + r;
                const int b = m >> 11, t = m & (TT - 1);
                const int k = k0 + c8s * 8;
                const int ks = k >> 9, ci = k & 511;
                src = A + ((size_t)(b * (TT + 2) + t + ks) * 512 + ci);
            } else {
                src = A + ((size_t)(bm + r) * K + k0 + c8s * 8);
            }
            gld16(src, Asb + (size_t)c * 8);
        }
        #pragma unroll
        for (int i = 0; i < 2; ++i) {
            const int c = tid + i * 256;
            const int r = c >> 2, c8 = c & 3;
            const int c8s = c8 ^ ((r >> 1) & 3);
            gld16(Bw + ((size_t)(bn + r) * K + k0 + c8s * 8), Bsb + (size_t)c * 8);
        }
    };

    floatx4 acc[MI][NJ];
    #pragma unroll
    for (int mi = 0; mi < MI; ++mi)
        #pragma unroll
        for (int nj = 0; nj < NJ; ++nj)
            acc[mi][nj] = (floatx4){0.f, 0.f, 0.f, 0.f};

    const int nt = K >> 5;
    stage(0, 0);
    __syncthreads();
    int cur = 0;
    for (int t = 0; t < nt; ++t) {
        if (t + 1 < nt) stage(cur ^ 1, (t + 1) * 32);

        const unsigned short* Asb = AsB + cur * ASTR;
        const unsigned short* Bsb = BsB + cur * BSTR;
        short8 av[MI], bv[NJ];
        #pragma unroll
        for (int mi = 0; mi < MI; ++mi) {
            const int row = mi * 16 + lr;
            av[mi] = *(const short8*)&Asb[row * 32 + (g ^ ((row >> 1) & 3)) * 8];
        }
        #pragma unroll
        for (int nj = 0; nj < NJ; ++nj) {
            const int row = wc * 32 + nj * 16 + lr;
            bv[nj] = *(const short8*)&Bsb[row * 32 + (g ^ ((row >> 1) & 3)) * 8];
        }
        __builtin_amdgcn_s_setprio(1);
        #pragma unroll
        for (int mi = 0; mi < MI; ++mi)
            #pragma unroll
            for (int nj = 0; nj < NJ; ++nj)
                acc[mi][nj] = __builtin_amdgcn_mfma_f32_16x16x32_bf16(av[mi], bv[nj], acc[mi][nj], 0, 0, 0);
        __builtin_amdgcn_s_setprio(0);
        __syncthreads();
        cur ^= 1;
    }

    float sa = 0.f, sb = 0.f;
    if (EPI == 5) { sa = sA[0]; sb = sB[0]; }
    #pragma unroll
    for (int mi = 0; mi < MI; ++mi)
        #pragma unroll
        for (int nj = 0; nj < NJ; ++nj)
            #pragma unroll
            for (int reg = 0; reg < 4; ++reg) {
                const int m = bm + mi * 16 + g * 4 + reg;
                const int n = bn + wc * 32 + nj * 16 + lr;
                float v = acc[mi][nj][reg] + bias[n];
                if (EPI == 0) {
                    const int b = m >> 11, t = m & (TT - 1);
                    if (n < 512) {
                        o1[(size_t)m * 512 + n] = f2bf(v * (0.125f * LOG2E));
                    } else if (n < 1024) {
                        o2[(size_t)m * 512 + (n - 512)] = f2bf(v);
                    } else {
                        const int c = n - 1024;
                        o3[(size_t)(b * 8 + (c >> 6)) * 64 * TT + (size_t)(c & 63) * TT + t] = f2bf(v);
                    }
                } else if (EPI == 1) {
                    o1[(size_t)m * 512 + n] = f2bf(v);
                } else if (EPI == 2) {
                    o1[(size_t)m * 512 + n] = f2bf(resf[(size_t)m * 512 + n] + gelu_f(v));
                } else if (EPI == 3) {
                    o1[(size_t)m * 512 + n] = f2bf(v + resf[(size_t)m * 512 + n]);
                } else if (EPI == 4) {
                    o1[(size_t)m * Nn + n] = f2bf(gelu_f(v));
                } else {
                    outf[(size_t)m * 512 + n] = sa * v + sb * bf2f(dsa[(size_t)m * 512 + n]);
                }
            }
}

template<int EPI, int AF>
__global__ __launch_bounds__(256, 4)
void gemm_k(const unsigned short* __restrict__ A, const unsigned short* __restrict__ Bw,
            const float* __restrict__ bias, const float* __restrict__ resf,
            const unsigned short* __restrict__ dsa,
            const float* __restrict__ sA, const float* __restrict__ sB,
            float* __restrict__ outf, unsigned short* __restrict__ o1,
            unsigned short* __restrict__ o2, unsigned short* __restrict__ o3,
            int Nn, int K)
{
    __shared__ unsigned short As[2 * 64 * 32];
    __shared__ unsigned short Bs[2 * 128 * 32];
    gemm_body<EPI, AF>(A, Bw, bias, resf, dsa, sA, sB, outf, o1, o2, o3,
                       Nn, K, gridDim.x, As, Bs);
}

// fused: z=0 -> dsa pointwise GEMM (K=512); z=1 -> conv premix (K=1536, im2col)
__global__ __launch_bounds__(256, 4)
void gemm_dual(const unsigned short* __restrict__ Gb, const unsigned short* __restrict__ Wpw,
               const float* __restrict__ dsa_pb, unsigned short* __restrict__ Db,
               const unsigned short* __restrict__ xpad, const unsigned short* __restrict__ Wcv,
               const float* __restrict__ conv1_b, const float* __restrict__ x,
               unsigned short* __restrict__ U1)
{
    __shared__ unsigned short As[2 * 64 * 32];
    __shared__ unsigned short Bs[2 * 128 * 32];
    if (blockIdx.z == 0)
        gemm_body<1, 0>(Gb, Wpw, dsa_pb, nullptr, nullptr, nullptr, nullptr,
                        nullptr, Db, nullptr, nullptr, 512, 512, gridDim.x, As, Bs);
    else
        gemm_body<2, 1>(xpad, Wcv, conv1_b, x, nullptr, nullptr, nullptr,
                        nullptr, U1, nullptr, nullptr, 512, 1536, gridDim.x, As, Bs);
}

// ---- MFMA flash attention, swapped S^T = mfma(K,Q): QBLK=64, KV split across
// wave-groups (waves 0-3: keys [0,1024), waves 4-7: keys [1024,2048)).
// Grid 1024 blocks, 49 KB LDS -> 3 blocks/CU. Max-free softmax, deferred l,
// cross-group o/l combine through LDS at the end.
__global__ __launch_bounds__(512, 6)
void attn_k(const unsigned short* __restrict__ Qb, const unsigned short* __restrict__ Kb,
            const unsigned short* __restrict__ Vtg, const float* __restrict__ Avec,
            const float* __restrict__ alpha_p, unsigned short* __restrict__ Oh)
{
    __shared__ unsigned short Kt[2][64 * 64];   // [group] 16 KB, XOR-swizzled rows
    __shared__ unsigned short Vt[2][64 * 64];   // 16 KB (V^T: rows=d, cols=key)
    __shared__ unsigned short P2[8][16 * 64];   // 16 KB (per-wave P^T spill; reused for o-combine)
    __shared__ float Lx[4][64];                 // 1 KB (l combine)

    const int tid = threadIdx.x;
    const int w = tid >> 6, lane = tid & 63;
    const int lr = lane & 15, g = lane >> 4;
    const int gsel = w >> 2, wq = w & 3;        // group, wave-within-group
    const int i0 = blockIdx.x * 64;
    const int h = blockIdx.y, b = blockIdx.z;
    const float* Ab = Avec + b * TT;
    const int q_glob = i0 + wq * 16 + lr;
    const float aqs = alpha_p[0] * LOG2E * Ab[q_glob];

    // ---- hoisted loop-invariant offsets ----
    int fOff[4][2];
    #pragma unroll
    for (int f = 0; f < 4; ++f) {
        const int row = f * 16 + lr;
        #pragma unroll
        for (int kk = 0; kk < 2; ++kk)
            fOff[f][kk] = row * 64 + (((kk * 64 + g * 16) ^ ((row & 7) << 4)) >> 1);
    }
    int pwOff[4], prOff[2];
    #pragma unroll
    for (int fc = 0; fc < 4; ++fc)
        pwOff[fc] = (lr * 128 + fc * 32 + g * 8) ^ ((lr & 7) << 4);
    #pragma unroll
    for (int kk = 0; kk < 2; ++kk)
        prOff[kk] = (lr * 128 + kk * 64 + g * 16) ^ ((lr & 7) << 4);

    const int j_s = tid >> 3, c8_s = tid & 7;
    const int wOff = j_s * 64 + (((c8_s * 16) ^ ((j_s & 7) << 4)) >> 1);

    // advancing global pointers; tile i belongs to group i (keys i*1024 + t*64)
    const unsigned short* kP = Kb + (size_t)(b * TT + j_s) * 512 + h * 64 + c8_s * 8;
    const unsigned short* vP = Vtg + (size_t)((b * 8 + h) * 64 + j_s) * TT + c8_s * 8;
    const float* aP = Ab + gsel * 1024 + g * 4;

    short8 kreg[2], vreg[2];
    auto load_tiles = [&]() {
        #pragma unroll
        for (int i = 0; i < 2; ++i) {
            kreg[i] = *(const short8*)(kP + (size_t)i * 1024 * 512);
            vreg[i] = *(const short8*)(vP + i * 1024);
        }
        kP += (size_t)64 * 512;
        vP += 64;
    };
    auto write_tiles = [&]() {
        #pragma unroll
        for (int i = 0; i < 2; ++i) {
            *(short8*)&Kt[i][wOff] = kreg[i];
            *(short8*)&Vt[i][wOff] = vreg[i];
        }
    };

    short8 qf[2];
    #pragma unroll
    for (int kk = 0; kk < 2; ++kk)
        qf[kk] = *(const short8*)&Qb[(size_t)(b * TT + q_glob) * 512 + h * 64 + kk * 32 + g * 8];

    float l_part = 0.f;
    floatx4 o[4];
    #pragma unroll
    for (int fd = 0; fd < 4; ++fd) o[fd] = (floatx4){0.f, 0.f, 0.f, 0.f};

    load_tiles();
    write_tiles();
    __syncthreads();

    for (int t = 0; t < 16; ++t) {
        if (t < 15) load_tiles();   // next 64-key chunk (per group) -> regs

        const unsigned short* ktb = &Kt[gsel][0];
        const unsigned short* vtb = &Vt[gsel][0];

        floatx4 akv[4];
        #pragma unroll
        for (int fc = 0; fc < 4; ++fc)
            akv[fc] = *(const floatx4*)(aP + fc * 16);
        aP += 64;

        floatx4 s[4];
        __builtin_amdgcn_s_setprio(1);
        #pragma unroll
        for (int fc = 0; fc < 4; ++fc) {
            const short8 kf0 = *(const short8*)&ktb[fOff[fc][0]];
            const short8 kf1 = *(const short8*)&ktb[fOff[fc][1]];
            floatx4 tacc = (floatx4){0.f, 0.f, 0.f, 0.f};
            tacc = __builtin_amdgcn_mfma_f32_16x16x32_bf16(kf0, qf[0], tacc, 0, 0, 0);
            tacc = __builtin_amdgcn_mfma_f32_16x16x32_bf16(kf1, qf[1], tacc, 0, 0, 0);
            s[fc] = tacc;
        }
        __builtin_amdgcn_s_setprio(0);
        #pragma unroll
        for (int fc = 0; fc < 4; ++fc)
            #pragma unroll
            for (int r = 0; r < 4; ++r) {
                const float p = __builtin_amdgcn_exp2f(s[fc][r] + aqs * akv[fc][r]);
                s[fc][r] = p;
                l_part += p;
            }

        #pragma unroll
        for (int fc = 0; fc < 4; ++fc) {
            uint2 pk;
            pk.x = cvtpk(s[fc][0], s[fc][1]);
            pk.y = cvtpk(s[fc][2], s[fc][3]);
            *(uint2*)((char*)&P2[w][0] + pwOff[fc]) = pk;
        }
        short8 pf[2];
        #pragma unroll
        for (int kk = 0; kk < 2; ++kk)
            pf[kk] = *(const short8*)((const char*)&P2[w][0] + prOff[kk]);
        __builtin_amdgcn_s_setprio(1);
        #pragma unroll
        for (int fd = 0; fd < 4; ++fd) {
            const short8 vf0 = *(const short8*)&vtb[fOff[fd][0]];
            const short8 vf1 = *(const short8*)&vtb[fOff[fd][1]];
            o[fd] = __builtin_amdgcn_mfma_f32_16x16x32_bf16(vf0, pf[0], o[fd], 0, 0, 0);
            o[fd] = __builtin_amdgcn_mfma_f32_16x16x32_bf16(vf1, pf[1], o[fd], 0, 0, 0);
        }
        __builtin_amdgcn_s_setprio(0);

        if (t < 15) {
            __syncthreads();    // all waves done READING Kt/Vt
            write_tiles();      // overwrite with next chunk
            __syncthreads();    // writes visible before next compute
        }
    }

    // ---- cross-group combine (group 1 -> LDS, group 0 reduces & stores) ----
    __syncthreads();
    float* Po = (float*)&P2[0][0];   // 16 KB: 4 waves x 64 lanes x 16 floats
    if (gsel == 1) {
        #pragma unroll
        for (int fd = 0; fd < 4; ++fd)
            *(floatx4*)&Po[((size_t)wq * 64 + lane) * 16 + fd * 4] = o[fd];
        Lx[wq][lane] = l_part;
    }
    __syncthreads();
    if (gsel == 0) {
        #pragma unroll
        for (int fd = 0; fd < 4; ++fd) {
            const floatx4 p = *(const floatx4*)&Po[((size_t)wq * 64 + lane) * 16 + fd * 4];
            o[fd] += p;
        }
        l_part += Lx[wq][lane];
        l_part += __shfl_xor(l_part, 16);
        l_part += __shfl_xor(l_part, 32);
        const float inv = 1.0f / l_part;
        const size_t orow = (size_t)(b * TT + q_glob) * 512 + h * 64;
        #pragma unroll
        for (int fd = 0; fd < 4; ++fd) {
            uint2 pk;
            pk.x = cvtpk(o[fd][0] * inv, o[fd][1] * inv);
            pk.y = cvtpk(o[fd][2] * inv, o[fd][3] * inv);
            *(uint2*)&Oh[orow + fd * 16 + g * 4] = pk;
        }
    }
}

// ---------------- launch ----------------
extern "C" void kernel_launch(void* const* d_in, const int* in_sizes, int n_in,
                              void* d_out, int out_size, void* d_ws, size_t ws_size,
                              hipStream_t stream)
{
    const float* x         = (const float*)d_in[0];
    const float* Avec      = (const float*)d_in[1];
    const float* alpha_b   = (const float*)d_in[2];
    const float* dst_alpha = (const float*)d_in[3];
    const float* dst_beta  = (const float*)d_in[4];
    const float* conv1_w   = (const float*)d_in[5];
    const float* conv1_b   = (const float*)d_in[6];
    const float* ln1_g     = (const float*)d_in[7];
    const float* ln1_b     = (const float*)d_in[8];
    const float* in_proj_w = (const float*)d_in[9];
    const float* in_proj_b = (const float*)d_in[10];
    const float* out_w     = (const float*)d_in[11];
    const float* out_b     = (const float*)d_in[12];
    const float* ln2_g     = (const float*)d_in[13];
    const float* ln2_b     = (const float*)d_in[14];
    const float* mlp_w1    = (const float*)d_in[15];
    const float* mlp_b1    = (const float*)d_in[16];
    const float* mlp_w2    = (const float*)d_in[17];
    const float* mlp_b2    = (const float*)d_in[18];
    const float* dsa_ln_g  = (const float*)d_in[19];
    const float* dsa_ln_b  = (const float*)d_in[20];
    const float* dsa_dw    = (const float*)d_in[21];
    const float* dsa_db    = (const float*)d_in[22];
    const float* dsa_pw    = (const float*)d_in[23];
    const float* dsa_pb    = (const float*)d_in[24];

    unsigned short* W    = (unsigned short*)d_ws;            // N1
    unsigned short* xpad = W + N1;                           // 4*2050*512
    unsigned short* Qb   = xpad + (size_t)4 * (TT + 2) * 512;
    unsigned short* Kbf  = Qb + N1;
    unsigned short* Vt   = Kbf + N1;
    unsigned short* Zb   = Vt + N1;
    unsigned short* Tb   = Qb;                               // [8192][2048] overlays Qb..Zb
    unsigned short* Gb   = Zb + N1;
    unsigned short* Db   = Gb + N1;
    unsigned short* U1   = Db + N1;
    unsigned short* U2   = U1 + N1;
    unsigned short* U3   = U2 + N1;

    const int off_qkv = 0, off_out = 786432, off_w1 = 1048576,
              off_w2 = 2097152, off_pw = 3145728, off_cv = 3407872;

    pack_w<<<16384, 256, 0, stream>>>(in_proj_w, out_w, mlp_w1, mlp_w2, dsa_pw, conv1_w, W);
    pack_x<<<MROWS, 256, 0, stream>>>(x, dsa_ln_g, dsa_ln_b, Zb, xpad);

    // --- DSA depthwise, then fused {dsa pointwise GEMM, conv premix GEMM} ---
    dwconv_k<<<MROWS, 256, 0, stream>>>(Zb, dsa_dw, dsa_db, Gb);
    gemm_dual<<<dim3(4, 128, 2), 256, 0, stream>>>(Gb, W + off_pw, dsa_pb, Db,
        xpad, W + off_cv, conv1_b, x, U1);
    ln_bf<<<MROWS, 256, 0, stream>>>(U1, ln1_g, ln1_b, U2);

    // --- qkv projection (q*0.125*log2e, k, v transposed) ---
    gemm_k<0, 0><<<dim3(12, 128), 256, 0, stream>>>(U2, W + off_qkv, in_proj_b,
        nullptr, nullptr, nullptr, nullptr, nullptr, Qb, Kbf, Vt, 1536, 512);

    // --- attention (QBLK=64, KV-split wave groups) ---
    attn_k<<<dim3(32, 8, 4), 512, 0, stream>>>(Qb, Kbf, Vt, Avec, alpha_b, U1);

    // --- out projection + residual, LN2 ---
    gemm_k<3, 0><<<dim3(4, 128), 256, 0, stream>>>(U1, W + off_out, out_b,
        x, nullptr, nullptr, nullptr, nullptr, U3, nullptr, nullptr, 512, 512);
    ln_bf<<<MROWS, 256, 0, stream>>>(U3, ln2_g, ln2_b, U2);

    // --- MLP ---
    gemm_k<4, 0><<<dim3(16, 128), 256, 0, stream>>>(U2, W + off_w1, mlp_b1,
        nullptr, nullptr, nullptr, nullptr, nullptr, Tb, nullptr, nullptr, 2048, 512);
    gemm_k<5, 0><<<dim3(4, 128), 256, 0, stream>>>(Tb, W + off_w2, mlp_b2,
        nullptr, Db, dst_alpha, dst_beta, (float*)d_out, nullptr, nullptr, nullptr,
        512, 2048);
}

// Round 16
// 251.821 us; speedup vs baseline: 1.3637x; 1.3637x over previous
//
#include <hip/hip_runtime.h>
#include <cmath>

typedef __attribute__((ext_vector_type(8))) short short8;
typedef __attribute__((ext_vector_type(4))) float floatx4;

#define TT 2048
#define CCH 512
#define MROWS 8192
static const size_t N1 = 4194304;   // 8192*512 elements
#define LOG2E 1.44269504088896340736f

__device__ __forceinline__ float gelu_f(float x) {
    return 0.5f * x * (1.0f + erff(x * 0.70710678118654752440f));
}
__device__ __forceinline__ unsigned short f2bf(float x) {
    union { float f; unsigned u; } v; v.f = x;
    unsigned r = v.u + 0x7fffu + ((v.u >> 16) & 1u);
    return (unsigned short)(r >> 16);
}
__device__ __forceinline__ float bf2f(unsigned short h) {
    union { unsigned u; float f; } v; v.u = ((unsigned)h) << 16;
    return v.f;
}
__device__ __forceinline__ unsigned cvtpk(float a, float b) {
    unsigned r;
    asm("v_cvt_pk_bf16_f32 %0, %1, %2" : "=v"(r) : "v"(a), "v"(b));
    return r;
}
__device__ __forceinline__ void gld16(const unsigned short* g, unsigned short* l) {
    __builtin_amdgcn_global_load_lds(
        (const __attribute__((address_space(1))) void*)g,
        (__attribute__((address_space(3))) void*)l, 16, 0, 0);
}

// ---------------- weight pack: fp32 -> bf16 (conv weights re-laid-out) ----------------
__global__ __launch_bounds__(256)
void pack_w(const float* __restrict__ qkvw, const float* __restrict__ outw,
            const float* __restrict__ w1, const float* __restrict__ w2,
            const float* __restrict__ pw, const float* __restrict__ cv,
            unsigned short* __restrict__ W)
{
    const int idx = blockIdx.x * 256 + threadIdx.x;
    float v;
    if (idx < 786432)            v = qkvw[idx];
    else if (idx < 1048576)      v = outw[idx - 786432];
    else if (idx < 2097152)      v = w1[idx - 1048576];
    else if (idx < 3145728)      v = w2[idx - 2097152];
    else if (idx < 3407872)      v = pw[idx - 3145728];
    else {
        const int l = idx - 3407872;
        const int n = l / 1536, k = l - n * 1536;
        const int ks = k >> 9, ci = k & 511;
        v = cv[n * 1536 + ci * 3 + ks];
    }
    W[idx] = f2bf(v);
}

// ---------------- fused: xpad bf16 (zero-padded rows) + DSA LayerNorm ----------------
__global__ __launch_bounds__(256)
void pack_x(const float* __restrict__ x, const float* __restrict__ gam,
            const float* __restrict__ bet, unsigned short* __restrict__ z,
            unsigned short* __restrict__ xpad)
{
    const int m = blockIdx.x, tid = threadIdx.x;
    const int b = m >> 11, t = m & (TT - 1);
    const float2 xv = *(const float2*)&x[(size_t)m * 512 + 2 * tid];
    float s = xv.x + xv.y, sq = xv.x * xv.x + xv.y * xv.y;
    #pragma unroll
    for (int off = 32; off; off >>= 1) { s += __shfl_xor(s, off); sq += __shfl_xor(sq, off); }
    __shared__ float ws[4], wq[4];
    const int wave = tid >> 6, lane = tid & 63;
    if (lane == 0) { ws[wave] = s; wq[wave] = sq; }
    __syncthreads();
    s = ws[0] + ws[1] + ws[2] + ws[3];
    sq = wq[0] + wq[1] + wq[2] + wq[3];
    const float mean = s * (1.0f / 512.0f);
    const float var = sq * (1.0f / 512.0f) - mean * mean;
    const float rstd = rsqrtf(var + 1e-5f);
    const float y0 = (xv.x - mean) * rstd * gam[2 * tid]     + bet[2 * tid];
    const float y1 = (xv.y - mean) * rstd * gam[2 * tid + 1] + bet[2 * tid + 1];
    *(unsigned*)&z[(size_t)m * 512 + 2 * tid] = ((unsigned)f2bf(y1) << 16) | f2bf(y0);
    *(unsigned*)&xpad[((size_t)(b * (TT + 2) + t + 1)) * 512 + 2 * tid] =
        ((unsigned)f2bf(xv.y) << 16) | f2bf(xv.x);
    if (t == 0)
        *(unsigned*)&xpad[((size_t)(b * (TT + 2))) * 512 + 2 * tid] = 0u;
    if (t == TT - 1)
        *(unsigned*)&xpad[((size_t)(b * (TT + 2) + TT + 1)) * 512 + 2 * tid] = 0u;
}

// ---------------- LayerNorm rows of 512, bf16 -> bf16 ----------------
__global__ __launch_bounds__(256)
void ln_bf(const unsigned short* __restrict__ in, const float* __restrict__ gam,
           const float* __restrict__ bet, unsigned short* __restrict__ out)
{
    const int m = blockIdx.x, tid = threadIdx.x;
    const unsigned pv = *(const unsigned*)&in[(size_t)m * 512 + 2 * tid];
    const float x0 = bf2f((unsigned short)pv), x1 = bf2f((unsigned short)(pv >> 16));
    float s = x0 + x1, sq = x0 * x0 + x1 * x1;
    #pragma unroll
    for (int off = 32; off; off >>= 1) { s += __shfl_xor(s, off); sq += __shfl_xor(sq, off); }
    __shared__ float ws[4], wq[4];
    const int wave = tid >> 6, lane = tid & 63;
    if (lane == 0) { ws[wave] = s; wq[wave] = sq; }
    __syncthreads();
    s = ws[0] + ws[1] + ws[2] + ws[3];
    sq = wq[0] + wq[1] + wq[2] + wq[3];
    const float mean = s * (1.0f / 512.0f);
    const float var = sq * (1.0f / 512.0f) - mean * mean;
    const float rstd = rsqrtf(var + 1e-5f);
    const float y0 = (x0 - mean) * rstd * gam[2 * tid]     + bet[2 * tid];
    const float y1 = (x1 - mean) * rstd * gam[2 * tid + 1] + bet[2 * tid + 1];
    *(unsigned*)&out[(size_t)m * 512 + 2 * tid] = ((unsigned)f2bf(y1) << 16) | f2bf(y0);
}

// ---------------- depthwise conv k=3 + bias + gelu ----------------
__global__ __launch_bounds__(256)
void dwconv_k(const unsigned short* __restrict__ z, const float* __restrict__ dw,
              const float* __restrict__ db, unsigned short* __restrict__ g)
{
    const int m = blockIdx.x, tid = threadIdx.x, t = m & (TT - 1);
    const int c = 2 * tid;
    const size_t base = (size_t)m * 512 + c;
    const unsigned vm = *(const unsigned*)&z[base];
    const unsigned va = (t > 0)      ? *(const unsigned*)&z[base - 512] : 0u;
    const unsigned vc = (t < TT - 1) ? *(const unsigned*)&z[base + 512] : 0u;
    float y[2];
    #pragma unroll
    for (int j = 0; j < 2; ++j) {
        const float a  = bf2f((unsigned short)(va >> (16 * j)));
        const float bb = bf2f((unsigned short)(vm >> (16 * j)));
        const float cc = bf2f((unsigned short)(vc >> (16 * j)));
        const int ch = c + j;
        y[j] = gelu_f(a * dw[ch * 3] + bb * dw[ch * 3 + 1] + cc * dw[ch * 3 + 2] + db[ch]);
    }
    *(unsigned*)&g[base] = ((unsigned)f2bf(y[1]) << 16) | f2bf(y[0]);
}

// --- bf16 MFMA GEMM body: TM=64/TN=128, NBUF=2, 24 KB LDS (6 blocks/CU),
//     simple 2-buffer loop (compiler waits, cross-block TLP hides latency),
//     bijective XCD-chunked block swizzle (same-A-panel blocks -> same XCD/L2).
// EPI: 0=qkv-split  1=bias->bf16  2=gelu+res(f32)->bf16  3=bias+res(f32)->bf16
//      4=bias+gelu->bf16  5=final combine -> f32
// AF : 0=A plain bf16 row-major   1=A from xpad (conv premix im2col)
template<int EPI, int AF>
__device__ __forceinline__ void gemm_body(
    const unsigned short* __restrict__ A, const unsigned short* __restrict__ Bw,
    const float* __restrict__ bias, const float* __restrict__ resf,
    const unsigned short* __restrict__ dsa,
    const float* __restrict__ sA, const float* __restrict__ sB,
    float* __restrict__ outf, unsigned short* __restrict__ o1,
    unsigned short* __restrict__ o2, unsigned short* __restrict__ o3,
    int Nn, int K, int gx, unsigned short* AsB, unsigned short* BsB)
{
    constexpr int MI = 4, NJ = 2;
    constexpr int ASTR = 64 * 32, BSTR = 128 * 32;

    // XCD-chunked bijective swizzle (nwg % 8 == 0 for all our launches)
    const int nwg = gx * gridDim.y;
    const int orig = blockIdx.x + gx * blockIdx.y;
    const int wg = (orig & 7) * (nwg >> 3) + (orig >> 3);
    const int bx = wg % gx, by = wg / gx;

    const int tid = threadIdx.x;
    const int bm = by * 64, bn = bx * 128;
    const int lane = tid & 63, w = tid >> 6;
    const int wc = w;                          // 4 waves along N
    const int lr = lane & 15, g = lane >> 4;

    auto stage = [&](int buf, int k0) {
        unsigned short* Asb = AsB + buf * ASTR;
        unsigned short* Bsb = BsB + buf * BSTR;
        {
            const int c = tid;
            const int r = c >> 2, c8 = c & 3;
            const int c8s = c8 ^ ((r >> 1) & 3);
            const unsigned short* src;
            if (AF == 1) {
                const int m = bm + r;
                const int b = m >> 11, t = m & (TT - 1);
                const int k = k0 + c8s * 8;
                const int ks = k >> 9, ci = k & 511;
                src = A + ((size_t)(b * (TT + 2) + t + ks) * 512 + ci);
            } else {
                src = A + ((size_t)(bm + r) * K + k0 + c8s * 8);
            }
            gld16(src, Asb + (size_t)c * 8);
        }
        #pragma unroll
        for (int i = 0; i < 2; ++i) {
            const int c = tid + i * 256;
            const int r = c >> 2, c8 = c & 3;
            const int c8s = c8 ^ ((r >> 1) & 3);
            gld16(Bw + ((size_t)(bn + r) * K + k0 + c8s * 8), Bsb + (size_t)c * 8);
        }
    };

    floatx4 acc[MI][NJ];
    #pragma unroll
    for (int mi = 0; mi < MI; ++mi)
        #pragma unroll
        for (int nj = 0; nj < NJ; ++nj)
            acc[mi][nj] = (floatx4){0.f, 0.f, 0.f, 0.f};

    const int nt = K >> 5;
    stage(0, 0);
    __syncthreads();
    int cur = 0;
    for (int t = 0; t < nt; ++t) {
        if (t + 1 < nt) stage(cur ^ 1, (t + 1) * 32);

        const unsigned short* Asb = AsB + cur * ASTR;
        const unsigned short* Bsb = BsB + cur * BSTR;
        short8 av[MI], bv[NJ];
        #pragma unroll
        for (int mi = 0; mi < MI; ++mi) {
            const int row = mi * 16 + lr;
            av[mi] = *(const short8*)&Asb[row * 32 + (g ^ ((row >> 1) & 3)) * 8];
        }
        #pragma unroll
        for (int nj = 0; nj < NJ; ++nj) {
            const int row = wc * 32 + nj * 16 + lr;
            bv[nj] = *(const short8*)&Bsb[row * 32 + (g ^ ((row >> 1) & 3)) * 8];
        }
        __builtin_amdgcn_s_setprio(1);
        #pragma unroll
        for (int mi = 0; mi < MI; ++mi)
            #pragma unroll
            for (int nj = 0; nj < NJ; ++nj)
                acc[mi][nj] = __builtin_amdgcn_mfma_f32_16x16x32_bf16(av[mi], bv[nj], acc[mi][nj], 0, 0, 0);
        __builtin_amdgcn_s_setprio(0);
        __syncthreads();
        cur ^= 1;
    }

    float sa = 0.f, sb = 0.f;
    if (EPI == 5) { sa = sA[0]; sb = sB[0]; }
    #pragma unroll
    for (int mi = 0; mi < MI; ++mi)
        #pragma unroll
        for (int nj = 0; nj < NJ; ++nj)
            #pragma unroll
            for (int reg = 0; reg < 4; ++reg) {
                const int m = bm + mi * 16 + g * 4 + reg;
                const int n = bn + wc * 32 + nj * 16 + lr;
                float v = acc[mi][nj][reg] + bias[n];
                if (EPI == 0) {
                    const int b = m >> 11, t = m & (TT - 1);
                    if (n < 512) {
                        o1[(size_t)m * 512 + n] = f2bf(v * (0.125f * LOG2E));
                    } else if (n < 1024) {
                        o2[(size_t)m * 512 + (n - 512)] = f2bf(v);
                    } else {
                        const int c = n - 1024;
                        o3[(size_t)(b * 8 + (c >> 6)) * 64 * TT + (size_t)(c & 63) * TT + t] = f2bf(v);
                    }
                } else if (EPI == 1) {
                    o1[(size_t)m * 512 + n] = f2bf(v);
                } else if (EPI == 2) {
                    o1[(size_t)m * 512 + n] = f2bf(resf[(size_t)m * 512 + n] + gelu_f(v));
                } else if (EPI == 3) {
                    o1[(size_t)m * 512 + n] = f2bf(v + resf[(size_t)m * 512 + n]);
                } else if (EPI == 4) {
                    o1[(size_t)m * Nn + n] = f2bf(gelu_f(v));
                } else {
                    outf[(size_t)m * 512 + n] = sa * v + sb * bf2f(dsa[(size_t)m * 512 + n]);
                }
            }
}

template<int EPI, int AF>
__global__ __launch_bounds__(256, 4)
void gemm_k(const unsigned short* __restrict__ A, const unsigned short* __restrict__ Bw,
            const float* __restrict__ bias, const float* __restrict__ resf,
            const unsigned short* __restrict__ dsa,
            const float* __restrict__ sA, const float* __restrict__ sB,
            float* __restrict__ outf, unsigned short* __restrict__ o1,
            unsigned short* __restrict__ o2, unsigned short* __restrict__ o3,
            int Nn, int K)
{
    __shared__ unsigned short As[2 * 64 * 32];
    __shared__ unsigned short Bs[2 * 128 * 32];
    gemm_body<EPI, AF>(A, Bw, bias, resf, dsa, sA, sB, outf, o1, o2, o3,
                       Nn, K, gridDim.x, As, Bs);
}

// fused: z=0 -> dsa pointwise GEMM (K=512); z=1 -> conv premix (K=1536, im2col)
__global__ __launch_bounds__(256, 4)
void gemm_dual(const unsigned short* __restrict__ Gb, const unsigned short* __restrict__ Wpw,
               const float* __restrict__ dsa_pb, unsigned short* __restrict__ Db,
               const unsigned short* __restrict__ xpad, const unsigned short* __restrict__ Wcv,
               const float* __restrict__ conv1_b, const float* __restrict__ x,
               unsigned short* __restrict__ U1)
{
    __shared__ unsigned short As[2 * 64 * 32];
    __shared__ unsigned short Bs[2 * 128 * 32];
    if (blockIdx.z == 0)
        gemm_body<1, 0>(Gb, Wpw, dsa_pb, nullptr, nullptr, nullptr, nullptr,
                        nullptr, Db, nullptr, nullptr, 512, 512, gridDim.x, As, Bs);
    else
        gemm_body<2, 1>(xpad, Wcv, conv1_b, x, nullptr, nullptr, nullptr,
                        nullptr, U1, nullptr, nullptr, 512, 1536, gridDim.x, As, Bs);
}

// ---- MFMA flash attention, swapped S^T = mfma(K,Q): 8 waves, QBLK=128, KVBLK=128 ----
// Max-free softmax; per-thread l accumulated across tiles, reduced once at the end.
// exp2 via native v_exp_f32 (scores are small & finite; libcall edge cases not needed).
__global__ __launch_bounds__(512, 2)
void attn_k(const unsigned short* __restrict__ Qb, const unsigned short* __restrict__ Kb,
            const unsigned short* __restrict__ Vtg, const float* __restrict__ Avec,
            const float* __restrict__ alpha_p, unsigned short* __restrict__ Oh)
{
    __shared__ unsigned short Kt[2][2][64 * 64];   // [buf][sub] 32 KB, XOR-swizzled rows
    __shared__ unsigned short Vt[2][2][64 * 64];   // 32 KB (V^T: rows=d, cols=key)
    __shared__ unsigned short P2[8][16 * 64];      // 16 KB (per-wave P^T spill)

    const int tid = threadIdx.x;
    const int w = tid >> 6, lane = tid & 63;
    const int lr = lane & 15, g = lane >> 4;
    const int i0 = blockIdx.x * 128;
    const int h = blockIdx.y, b = blockIdx.z;
    const float* Ab = Avec + b * TT;
    const int q_glob = i0 + w * 16 + lr;
    const float aqs = alpha_p[0] * LOG2E * Ab[q_glob];

    // ---- hoisted loop-invariant offsets ----
    int fOff[4][2];
    #pragma unroll
    for (int f = 0; f < 4; ++f) {
        const int row = f * 16 + lr;
        #pragma unroll
        for (int kk = 0; kk < 2; ++kk)
            fOff[f][kk] = row * 64 + (((kk * 64 + g * 16) ^ ((row & 7) << 4)) >> 1);
    }
    int pwOff[4], prOff[2];
    #pragma unroll
    for (int fc = 0; fc < 4; ++fc)
        pwOff[fc] = (lr * 128 + fc * 32 + g * 8) ^ ((lr & 7) << 4);
    #pragma unroll
    for (int kk = 0; kk < 2; ++kk)
        prOff[kk] = (lr * 128 + kk * 64 + g * 16) ^ ((lr & 7) << 4);

    const int j_s = tid >> 3, c8_s = tid & 7;
    const int wOff = j_s * 64 + (((c8_s * 16) ^ ((j_s & 7) << 4)) >> 1);

    const unsigned short* kP = Kb + (size_t)(b * TT + j_s) * 512 + h * 64 + c8_s * 8;
    const unsigned short* vP = Vtg + (size_t)((b * 8 + h) * 64 + j_s) * TT + c8_s * 8;
    const float* aP = Ab + g * 4;

    short8 kreg[2], vreg[2];
    auto load_tiles = [&]() {
        #pragma unroll
        for (int i = 0; i < 2; ++i) {
            kreg[i] = *(const short8*)(kP + (size_t)i * 64 * 512);
            vreg[i] = *(const short8*)(vP + i * 64);
        }
        kP += (size_t)128 * 512;
        vP += 128;
    };
    auto write_tiles = [&](int buf) {
        #pragma unroll
        for (int i = 0; i < 2; ++i) {
            *(short8*)&Kt[buf][i][wOff] = kreg[i];
            *(short8*)&Vt[buf][i][wOff] = vreg[i];
        }
    };

    short8 qf[2];
    #pragma unroll
    for (int kk = 0; kk < 2; ++kk)
        qf[kk] = *(const short8*)&Qb[(size_t)(b * TT + q_glob) * 512 + h * 64 + kk * 32 + g * 8];

    float l_part = 0.f;
    floatx4 o[4];
    #pragma unroll
    for (int fd = 0; fd < 4; ++fd) o[fd] = (floatx4){0.f, 0.f, 0.f, 0.f};

    load_tiles();
    write_tiles(0);
    __syncthreads();
    int cur = 0;

    for (int t = 0; t < 16; ++t) {
        if (t < 15) load_tiles();

        #pragma unroll
        for (int st = 0; st < 2; ++st) {
            const unsigned short* ktb = &Kt[cur][st][0];
            const unsigned short* vtb = &Vt[cur][st][0];

            floatx4 akv[4];
            #pragma unroll
            for (int fc = 0; fc < 4; ++fc)
                akv[fc] = *(const floatx4*)(aP + fc * 16);
            aP += 64;

            floatx4 s[4];
            #pragma unroll
            for (int fc = 0; fc < 4; ++fc) {
                const short8 kf0 = *(const short8*)&ktb[fOff[fc][0]];
                const short8 kf1 = *(const short8*)&ktb[fOff[fc][1]];
                floatx4 tacc = (floatx4){0.f, 0.f, 0.f, 0.f};
                __builtin_amdgcn_s_setprio(1);
                tacc = __builtin_amdgcn_mfma_f32_16x16x32_bf16(kf0, qf[0], tacc, 0, 0, 0);
                tacc = __builtin_amdgcn_mfma_f32_16x16x32_bf16(kf1, qf[1], tacc, 0, 0, 0);
                __builtin_amdgcn_s_setprio(0);
                s[fc] = tacc;
            }
            #pragma unroll
            for (int fc = 0; fc < 4; ++fc)
                #pragma unroll
                for (int r = 0; r < 4; ++r) {
                    const float p = __builtin_amdgcn_exp2f(s[fc][r] + aqs * akv[fc][r]);
                    s[fc][r] = p;
                    l_part += p;
                }

            #pragma unroll
            for (int fc = 0; fc < 4; ++fc) {
                uint2 pk;
                pk.x = cvtpk(s[fc][0], s[fc][1]);
                pk.y = cvtpk(s[fc][2], s[fc][3]);
                *(uint2*)((char*)&P2[w][0] + pwOff[fc]) = pk;
            }
            short8 pf[2];
            #pragma unroll
            for (int kk = 0; kk < 2; ++kk)
                pf[kk] = *(const short8*)((const char*)&P2[w][0] + prOff[kk]);
            #pragma unroll
            for (int fd = 0; fd < 4; ++fd) {
                const short8 vf0 = *(const short8*)&vtb[fOff[fd][0]];
                const short8 vf1 = *(const short8*)&vtb[fOff[fd][1]];
                __builtin_amdgcn_s_setprio(1);
                o[fd] = __builtin_amdgcn_mfma_f32_16x16x32_bf16(vf0, pf[0], o[fd], 0, 0, 0);
                o[fd] = __builtin_amdgcn_mfma_f32_16x16x32_bf16(vf1, pf[1], o[fd], 0, 0, 0);
                __builtin_amdgcn_s_setprio(0);
            }
        }

        if (t < 15) write_tiles(cur ^ 1);
        __syncthreads();
        cur ^= 1;
    }

    l_part += __shfl_xor(l_part, 16);
    l_part += __shfl_xor(l_part, 32);
    const float inv = 1.0f / l_part;
    const size_t orow = (size_t)(b * TT + q_glob) * 512 + h * 64;
    #pragma unroll
    for (int fd = 0; fd < 4; ++fd) {
        uint2 pk;
        pk.x = cvtpk(o[fd][0] * inv, o[fd][1] * inv);
        pk.y = cvtpk(o[fd][2] * inv, o[fd][3] * inv);
        *(uint2*)&Oh[orow + fd * 16 + g * 4] = pk;
    }
}

// ---------------- launch ----------------
extern "C" void kernel_launch(void* const* d_in, const int* in_sizes, int n_in,
                              void* d_out, int out_size, void* d_ws, size_t ws_size,
                              hipStream_t stream)
{
    const float* x         = (const float*)d_in[0];
    const float* Avec      = (const float*)d_in[1];
    const float* alpha_b   = (const float*)d_in[2];
    const float* dst_alpha = (const float*)d_in[3];
    const float* dst_beta  = (const float*)d_in[4];
    const float* conv1_w   = (const float*)d_in[5];
    const float* conv1_b   = (const float*)d_in[6];
    const float* ln1_g     = (const float*)d_in[7];
    const float* ln1_b     = (const float*)d_in[8];
    const float* in_proj_w = (const float*)d_in[9];
    const float* in_proj_b = (const float*)d_in[10];
    const float* out_w     = (const float*)d_in[11];
    const float* out_b     = (const float*)d_in[12];
    const float* ln2_g     = (const float*)d_in[13];
    const float* ln2_b     = (const float*)d_in[14];
    const float* mlp_w1    = (const float*)d_in[15];
    const float* mlp_b1    = (const float*)d_in[16];
    const float* mlp_w2    = (const float*)d_in[17];
    const float* mlp_b2    = (const float*)d_in[18];
    const float* dsa_ln_g  = (const float*)d_in[19];
    const float* dsa_ln_b  = (const float*)d_in[20];
    const float* dsa_dw    = (const float*)d_in[21];
    const float* dsa_db    = (const float*)d_in[22];
    const float* dsa_pw    = (const float*)d_in[23];
    const float* dsa_pb    = (const float*)d_in[24];

    unsigned short* W    = (unsigned short*)d_ws;            // N1
    unsigned short* xpad = W + N1;                           // 4*2050*512
    unsigned short* Qb   = xpad + (size_t)4 * (TT + 2) * 512;
    unsigned short* Kbf  = Qb + N1;
    unsigned short* Vt   = Kbf + N1;
    unsigned short* Zb   = Vt + N1;
    unsigned short* Tb   = Qb;                               // [8192][2048] overlays Qb..Zb
    unsigned short* Gb   = Zb + N1;
    unsigned short* Db   = Gb + N1;
    unsigned short* U1   = Db + N1;
    unsigned short* U2   = U1 + N1;
    unsigned short* U3   = U2 + N1;

    const int off_qkv = 0, off_out = 786432, off_w1 = 1048576,
              off_w2 = 2097152, off_pw = 3145728, off_cv = 3407872;

    pack_w<<<16384, 256, 0, stream>>>(in_proj_w, out_w, mlp_w1, mlp_w2, dsa_pw, conv1_w, W);
    pack_x<<<MROWS, 256, 0, stream>>>(x, dsa_ln_g, dsa_ln_b, Zb, xpad);

    // --- DSA depthwise, then fused {dsa pointwise GEMM, conv premix GEMM} ---
    dwconv_k<<<MROWS, 256, 0, stream>>>(Zb, dsa_dw, dsa_db, Gb);
    gemm_dual<<<dim3(4, 128, 2), 256, 0, stream>>>(Gb, W + off_pw, dsa_pb, Db,
        xpad, W + off_cv, conv1_b, x, U1);
    ln_bf<<<MROWS, 256, 0, stream>>>(U1, ln1_g, ln1_b, U2);

    // --- qkv projection (q*0.125*log2e, k, v transposed) ---
    gemm_k<0, 0><<<dim3(12, 128), 256, 0, stream>>>(U2, W + off_qkv, in_proj_b,
        nullptr, nullptr, nullptr, nullptr, nullptr, Qb, Kbf, Vt, 1536, 512);

    // --- attention ---
    attn_k<<<dim3(16, 8, 4), 512, 0, stream>>>(Qb, Kbf, Vt, Avec, alpha_b, U1);

    // --- out projection + residual, LN2 ---
    gemm_k<3, 0><<<dim3(4, 128), 256, 0, stream>>>(U1, W + off_out, out_b,
        x, nullptr, nullptr, nullptr, nullptr, U3, nullptr, nullptr, 512, 512);
    ln_bf<<<MROWS, 256, 0, stream>>>(U3, ln2_g, ln2_b, U2);

    // --- MLP ---
    gemm_k<4, 0><<<dim3(16, 128), 256, 0, stream>>>(U2, W + off_w1, mlp_b1,
        nullptr, nullptr, nullptr, nullptr, nullptr, Tb, nullptr, nullptr, 2048, 512);
    gemm_k<5, 0><<<dim3(4, 128), 256, 0, stream>>>(Tb, W + off_w2, mlp_b2,
        nullptr, Db, dst_alpha, dst_beta, (float*)d_out, nullptr, nullptr, nullptr,
        512, 2048);
}

// Round 17
// 248.905 us; speedup vs baseline: 1.3796x; 1.0117x over previous
//
#include <hip/hip_runtime.h>
#include <cmath>

typedef __attribute__((ext_vector_type(8))) short short8;
typedef __attribute__((ext_vector_type(4))) float floatx4;

#define TT 2048
#define CCH 512
#define MROWS 8192
static const size_t N1 = 4194304;   // 8192*512 elements
#define LOG2E 1.44269504088896340736f

__device__ __forceinline__ float gelu_f(float x) {
    return 0.5f * x * (1.0f + erff(x * 0.70710678118654752440f));
}
__device__ __forceinline__ unsigned short f2bf(float x) {
    union { float f; unsigned u; } v; v.f = x;
    unsigned r = v.u + 0x7fffu + ((v.u >> 16) & 1u);
    return (unsigned short)(r >> 16);
}
__device__ __forceinline__ float bf2f(unsigned short h) {
    union { unsigned u; float f; } v; v.u = ((unsigned)h) << 16;
    return v.f;
}
__device__ __forceinline__ unsigned cvtpk(float a, float b) {
    unsigned r;
    asm("v_cvt_pk_bf16_f32 %0, %1, %2" : "=v"(r) : "v"(a), "v"(b));
    return r;
}
__device__ __forceinline__ void gld16(const unsigned short* g, unsigned short* l) {
    __builtin_amdgcn_global_load_lds(
        (const __attribute__((address_space(1))) void*)g,
        (__attribute__((address_space(3))) void*)l, 16, 0, 0);
}

// ---------------- weight pack: fp32 -> bf16 (conv weights re-laid-out) ----------------
__global__ __launch_bounds__(256)
void pack_w(const float* __restrict__ qkvw, const float* __restrict__ outw,
            const float* __restrict__ w1, const float* __restrict__ w2,
            const float* __restrict__ pw, const float* __restrict__ cv,
            unsigned short* __restrict__ W)
{
    const int idx = blockIdx.x * 256 + threadIdx.x;
    float v;
    if (idx < 786432)            v = qkvw[idx];
    else if (idx < 1048576)      v = outw[idx - 786432];
    else if (idx < 2097152)      v = w1[idx - 1048576];
    else if (idx < 3145728)      v = w2[idx - 2097152];
    else if (idx < 3407872)      v = pw[idx - 3145728];
    else {
        const int l = idx - 3407872;
        const int n = l / 1536, k = l - n * 1536;
        const int ks = k >> 9, ci = k & 511;
        v = cv[n * 1536 + ci * 3 + ks];
    }
    W[idx] = f2bf(v);
}

// ---------------- fused: xpad bf16 (zero-padded rows) + DSA LayerNorm ----------------
__global__ __launch_bounds__(256)
void pack_x(const float* __restrict__ x, const float* __restrict__ gam,
            const float* __restrict__ bet, unsigned short* __restrict__ z,
            unsigned short* __restrict__ xpad)
{
    const int m = blockIdx.x, tid = threadIdx.x;
    const int b = m >> 11, t = m & (TT - 1);
    const float2 xv = *(const float2*)&x[(size_t)m * 512 + 2 * tid];
    float s = xv.x + xv.y, sq = xv.x * xv.x + xv.y * xv.y;
    #pragma unroll
    for (int off = 32; off; off >>= 1) { s += __shfl_xor(s, off); sq += __shfl_xor(sq, off); }
    __shared__ float ws[4], wq[4];
    const int wave = tid >> 6, lane = tid & 63;
    if (lane == 0) { ws[wave] = s; wq[wave] = sq; }
    __syncthreads();
    s = ws[0] + ws[1] + ws[2] + ws[3];
    sq = wq[0] + wq[1] + wq[2] + wq[3];
    const float mean = s * (1.0f / 512.0f);
    const float var = sq * (1.0f / 512.0f) - mean * mean;
    const float rstd = rsqrtf(var + 1e-5f);
    const float y0 = (xv.x - mean) * rstd * gam[2 * tid]     + bet[2 * tid];
    const float y1 = (xv.y - mean) * rstd * gam[2 * tid + 1] + bet[2 * tid + 1];
    *(unsigned*)&z[(size_t)m * 512 + 2 * tid] = ((unsigned)f2bf(y1) << 16) | f2bf(y0);
    *(unsigned*)&xpad[((size_t)(b * (TT + 2) + t + 1)) * 512 + 2 * tid] =
        ((unsigned)f2bf(xv.y) << 16) | f2bf(xv.x);
    if (t == 0)
        *(unsigned*)&xpad[((size_t)(b * (TT + 2))) * 512 + 2 * tid] = 0u;
    if (t == TT - 1)
        *(unsigned*)&xpad[((size_t)(b * (TT + 2) + TT + 1)) * 512 + 2 * tid] = 0u;
}

// ---------------- LayerNorm rows of 512, bf16 -> bf16 ----------------
__global__ __launch_bounds__(256)
void ln_bf(const unsigned short* __restrict__ in, const float* __restrict__ gam,
           const float* __restrict__ bet, unsigned short* __restrict__ out)
{
    const int m = blockIdx.x, tid = threadIdx.x;
    const unsigned pv = *(const unsigned*)&in[(size_t)m * 512 + 2 * tid];
    const float x0 = bf2f((unsigned short)pv), x1 = bf2f((unsigned short)(pv >> 16));
    float s = x0 + x1, sq = x0 * x0 + x1 * x1;
    #pragma unroll
    for (int off = 32; off; off >>= 1) { s += __shfl_xor(s, off); sq += __shfl_xor(sq, off); }
    __shared__ float ws[4], wq[4];
    const int wave = tid >> 6, lane = tid & 63;
    if (lane == 0) { ws[wave] = s; wq[wave] = sq; }
    __syncthreads();
    s = ws[0] + ws[1] + ws[2] + ws[3];
    sq = wq[0] + wq[1] + wq[2] + wq[3];
    const float mean = s * (1.0f / 512.0f);
    const float var = sq * (1.0f / 512.0f) - mean * mean;
    const float rstd = rsqrtf(var + 1e-5f);
    const float y0 = (x0 - mean) * rstd * gam[2 * tid]     + bet[2 * tid];
    const float y1 = (x1 - mean) * rstd * gam[2 * tid + 1] + bet[2 * tid + 1];
    *(unsigned*)&out[(size_t)m * 512 + 2 * tid] = ((unsigned)f2bf(y1) << 16) | f2bf(y0);
}

// ---------------- depthwise conv k=3 + bias + gelu ----------------
__global__ __launch_bounds__(256)
void dwconv_k(const unsigned short* __restrict__ z, const float* __restrict__ dw,
              const float* __restrict__ db, unsigned short* __restrict__ g)
{
    const int m = blockIdx.x, tid = threadIdx.x, t = m & (TT - 1);
    const int c = 2 * tid;
    const size_t base = (size_t)m * 512 + c;
    const unsigned vm = *(const unsigned*)&z[base];
    const unsigned va = (t > 0)      ? *(const unsigned*)&z[base - 512] : 0u;
    const unsigned vc = (t < TT - 1) ? *(const unsigned*)&z[base + 512] : 0u;
    float y[2];
    #pragma unroll
    for (int j = 0; j < 2; ++j) {
        const float a  = bf2f((unsigned short)(va >> (16 * j)));
        const float bb = bf2f((unsigned short)(vm >> (16 * j)));
        const float cc = bf2f((unsigned short)(vc >> (16 * j)));
        const int ch = c + j;
        y[j] = gelu_f(a * dw[ch * 3] + bb * dw[ch * 3 + 1] + cc * dw[ch * 3 + 2] + db[ch]);
    }
    *(unsigned*)&g[base] = ((unsigned)f2bf(y[1]) << 16) | f2bf(y[0]);
}

// --- bf16 MFMA GEMM body: TM=64/TN=128, NBUF=2, 24 KB LDS (6 blocks/CU),
//     simple 2-buffer loop, bijective XCD-chunked block swizzle.
// EPI: 0=qkv-split  1=bias->bf16  2=gelu+res(f32)->bf16  3=bias+res(f32)->bf16
//      4=bias+gelu->bf16  5=final combine -> f32
// AF : 0=A plain bf16 row-major   1=A from xpad (conv premix im2col)
template<int EPI, int AF>
__device__ __forceinline__ void gemm_body(
    const unsigned short* __restrict__ A, const unsigned short* __restrict__ Bw,
    const float* __restrict__ bias, const float* __restrict__ resf,
    const unsigned short* __restrict__ dsa,
    const float* __restrict__ sA, const float* __restrict__ sB,
    float* __restrict__ outf, unsigned short* __restrict__ o1,
    unsigned short* __restrict__ o2, unsigned short* __restrict__ o3,
    int Nn, int K, int gx, unsigned short* AsB, unsigned short* BsB)
{
    constexpr int MI = 4, NJ = 2;
    constexpr int ASTR = 64 * 32, BSTR = 128 * 32;

    const int nwg = gx * gridDim.y;
    const int orig = blockIdx.x + gx * blockIdx.y;
    const int wg = (orig & 7) * (nwg >> 3) + (orig >> 3);
    const int bx = wg % gx, by = wg / gx;

    const int tid = threadIdx.x;
    const int bm = by * 64, bn = bx * 128;
    const int lane = tid & 63, w = tid >> 6;
    const int wc = w;
    const int lr = lane & 15, g = lane >> 4;

    auto stage = [&](int buf, int k0) {
        unsigned short* Asb = AsB + buf * ASTR;
        unsigned short* Bsb = BsB + buf * BSTR;
        {
            const int c = tid;
            const int r = c >> 2, c8 = c & 3;
            const int c8s = c8 ^ ((r >> 1) & 3);
            const unsigned short* src;
            if (AF == 1) {
                const int m = bm + r;
                const int b = m >> 11, t = m & (TT - 1);
                const int k = k0 + c8s * 8;
                const int ks = k >> 9, ci = k & 511;
                src = A + ((size_t)(b * (TT + 2) + t + ks) * 512 + ci);
            } else {
                src = A + ((size_t)(bm + r) * K + k0 + c8s * 8);
            }
            gld16(src, Asb + (size_t)c * 8);
        }
        #pragma unroll
        for (int i = 0; i < 2; ++i) {
            const int c = tid + i * 256;
            const int r = c >> 2, c8 = c & 3;
            const int c8s = c8 ^ ((r >> 1) & 3);
            gld16(Bw + ((size_t)(bn + r) * K + k0 + c8s * 8), Bsb + (size_t)c * 8);
        }
    };

    floatx4 acc[MI][NJ];
    #pragma unroll
    for (int mi = 0; mi < MI; ++mi)
        #pragma unroll
        for (int nj = 0; nj < NJ; ++nj)
            acc[mi][nj] = (floatx4){0.f, 0.f, 0.f, 0.f};

    const int nt = K >> 5;
    stage(0, 0);
    __syncthreads();
    int cur = 0;
    for (int t = 0; t < nt; ++t) {
        if (t + 1 < nt) stage(cur ^ 1, (t + 1) * 32);

        const unsigned short* Asb = AsB + cur * ASTR;
        const unsigned short* Bsb = BsB + cur * BSTR;
        short8 av[MI], bv[NJ];
        #pragma unroll
        for (int mi = 0; mi < MI; ++mi) {
            const int row = mi * 16 + lr;
            av[mi] = *(const short8*)&Asb[row * 32 + (g ^ ((row >> 1) & 3)) * 8];
        }
        #pragma unroll
        for (int nj = 0; nj < NJ; ++nj) {
            const int row = wc * 32 + nj * 16 + lr;
            bv[nj] = *(const short8*)&Bsb[row * 32 + (g ^ ((row >> 1) & 3)) * 8];
        }
        __builtin_amdgcn_s_setprio(1);
        #pragma unroll
        for (int mi = 0; mi < MI; ++mi)
            #pragma unroll
            for (int nj = 0; nj < NJ; ++nj)
                acc[mi][nj] = __builtin_amdgcn_mfma_f32_16x16x32_bf16(av[mi], bv[nj], acc[mi][nj], 0, 0, 0);
        __builtin_amdgcn_s_setprio(0);
        __syncthreads();
        cur ^= 1;
    }

    float sa = 0.f, sb = 0.f;
    if (EPI == 5) { sa = sA[0]; sb = sB[0]; }
    #pragma unroll
    for (int mi = 0; mi < MI; ++mi)
        #pragma unroll
        for (int nj = 0; nj < NJ; ++nj)
            #pragma unroll
            for (int reg = 0; reg < 4; ++reg) {
                const int m = bm + mi * 16 + g * 4 + reg;
                const int n = bn + wc * 32 + nj * 16 + lr;
                float v = acc[mi][nj][reg] + bias[n];
                if (EPI == 0) {
                    const int b = m >> 11, t = m & (TT - 1);
                    if (n < 512) {
                        o1[(size_t)m * 512 + n] = f2bf(v * (0.125f * LOG2E));
                    } else if (n < 1024) {
                        o2[(size_t)m * 512 + (n - 512)] = f2bf(v);
                    } else {
                        const int c = n - 1024;
                        o3[(size_t)(b * 8 + (c >> 6)) * 64 * TT + (size_t)(c & 63) * TT + t] = f2bf(v);
                    }
                } else if (EPI == 1) {
                    o1[(size_t)m * 512 + n] = f2bf(v);
                } else if (EPI == 2) {
                    o1[(size_t)m * 512 + n] = f2bf(resf[(size_t)m * 512 + n] + gelu_f(v));
                } else if (EPI == 3) {
                    o1[(size_t)m * 512 + n] = f2bf(v + resf[(size_t)m * 512 + n]);
                } else if (EPI == 4) {
                    o1[(size_t)m * Nn + n] = f2bf(gelu_f(v));
                } else {
                    outf[(size_t)m * 512 + n] = sa * v + sb * bf2f(dsa[(size_t)m * 512 + n]);
                }
            }
}

template<int EPI, int AF>
__global__ __launch_bounds__(256, 4)
void gemm_k(const unsigned short* __restrict__ A, const unsigned short* __restrict__ Bw,
            const float* __restrict__ bias, const float* __restrict__ resf,
            const unsigned short* __restrict__ dsa,
            const float* __restrict__ sA, const float* __restrict__ sB,
            float* __restrict__ outf, unsigned short* __restrict__ o1,
            unsigned short* __restrict__ o2, unsigned short* __restrict__ o3,
            int Nn, int K)
{
    __shared__ unsigned short As[2 * 64 * 32];
    __shared__ unsigned short Bs[2 * 128 * 32];
    gemm_body<EPI, AF>(A, Bw, bias, resf, dsa, sA, sB, outf, o1, o2, o3,
                       Nn, K, gridDim.x, As, Bs);
}

// fused: z=0 -> dsa pointwise GEMM (K=512); z=1 -> conv premix (K=1536, im2col)
__global__ __launch_bounds__(256, 4)
void gemm_dual(const unsigned short* __restrict__ Gb, const unsigned short* __restrict__ Wpw,
               const float* __restrict__ dsa_pb, unsigned short* __restrict__ Db,
               const unsigned short* __restrict__ xpad, const unsigned short* __restrict__ Wcv,
               const float* __restrict__ conv1_b, const float* __restrict__ x,
               unsigned short* __restrict__ U1)
{
    __shared__ unsigned short As[2 * 64 * 32];
    __shared__ unsigned short Bs[2 * 128 * 32];
    if (blockIdx.z == 0)
        gemm_body<1, 0>(Gb, Wpw, dsa_pb, nullptr, nullptr, nullptr, nullptr,
                        nullptr, Db, nullptr, nullptr, 512, 512, gridDim.x, As, Bs);
    else
        gemm_body<2, 1>(xpad, Wcv, conv1_b, x, nullptr, nullptr, nullptr,
                        nullptr, U1, nullptr, nullptr, 512, 1536, gridDim.x, As, Bs);
}

// ---- MFMA flash attention, swapped S^T = mfma(K,Q): 8 waves, QBLK=128, KVBLK=128 ----
// K/V staged via global_load_lds with pre-swizzled SOURCE + linear LDS dest (rule 21);
// LDS image identical to the previous reg-staged swizzled layout. Max-free softmax,
// deferred l, native v_exp_f32.
__global__ __launch_bounds__(512, 2)
void attn_k(const unsigned short* __restrict__ Qb, const unsigned short* __restrict__ Kb,
            const unsigned short* __restrict__ Vtg, const float* __restrict__ Avec,
            const float* __restrict__ alpha_p, unsigned short* __restrict__ Oh)
{
    __shared__ unsigned short Kt[2][2][64 * 64];   // [buf][sub] 32 KB, swizzled layout
    __shared__ unsigned short Vt[2][2][64 * 64];   // 32 KB (V^T: rows=d, cols=key)
    __shared__ unsigned short P2[8][16 * 64];      // 16 KB (per-wave P^T spill)

    const int tid = threadIdx.x;
    const int w = tid >> 6, lane = tid & 63;
    const int lr = lane & 15, g = lane >> 4;
    const int i0 = blockIdx.x * 128;
    const int h = blockIdx.y, b = blockIdx.z;
    const float* Ab = Avec + b * TT;
    const int q_glob = i0 + w * 16 + lr;
    const float aqs = alpha_p[0] * LOG2E * Ab[q_glob];

    // ---- hoisted loop-invariant offsets ----
    int fOff[4][2];
    #pragma unroll
    for (int f = 0; f < 4; ++f) {
        const int row = f * 16 + lr;
        #pragma unroll
        for (int kk = 0; kk < 2; ++kk)
            fOff[f][kk] = row * 64 + (((kk * 64 + g * 16) ^ ((row & 7) << 4)) >> 1);
    }
    int pwOff[4], prOff[2];
    #pragma unroll
    for (int fc = 0; fc < 4; ++fc)
        pwOff[fc] = (lr * 128 + fc * 32 + g * 8) ^ ((lr & 7) << 4);
    #pragma unroll
    for (int kk = 0; kk < 2; ++kk)
        prOff[kk] = (lr * 128 + kk * 64 + g * 16) ^ ((lr & 7) << 4);

    // staging: 512 threads; row j_s, 16B chunk c8_s; linear LDS dest, swizzled SOURCE
    const int j_s = tid >> 3, c8_s = tid & 7;
    const int c8sw = c8_s ^ (j_s & 7);
    const int dOff = j_s * 64 + c8_s * 8;

    const unsigned short* kBase = Kb + (size_t)(b * TT + j_s) * 512 + h * 64 + c8sw * 8;
    const unsigned short* vBase = Vtg + (size_t)((b * 8 + h) * 64 + j_s) * TT + c8sw * 8;

    auto stage = [&](int buf, int kv0) {
        #pragma unroll
        for (int i = 0; i < 2; ++i) {
            gld16(kBase + (size_t)(kv0 + i * 64) * 512, &Kt[buf][i][dOff]);
            gld16(vBase + kv0 + i * 64, &Vt[buf][i][dOff]);
        }
    };

    const float* aP = Ab + g * 4;

    short8 qf[2];
    #pragma unroll
    for (int kk = 0; kk < 2; ++kk)
        qf[kk] = *(const short8*)&Qb[(size_t)(b * TT + q_glob) * 512 + h * 64 + kk * 32 + g * 8];

    float l_part = 0.f;
    floatx4 o[4];
    #pragma unroll
    for (int fd = 0; fd < 4; ++fd) o[fd] = (floatx4){0.f, 0.f, 0.f, 0.f};

    stage(0, 0);
    __syncthreads();
    int cur = 0;

    for (int t = 0; t < 16; ++t) {
        if (t < 15) stage(cur ^ 1, (t + 1) * 128);   // direct-to-LDS, spans compute phase

        #pragma unroll
        for (int st = 0; st < 2; ++st) {
            const unsigned short* ktb = &Kt[cur][st][0];
            const unsigned short* vtb = &Vt[cur][st][0];

            floatx4 akv[4];
            #pragma unroll
            for (int fc = 0; fc < 4; ++fc)
                akv[fc] = *(const floatx4*)(aP + fc * 16);
            aP += 64;

            floatx4 s[4];
            #pragma unroll
            for (int fc = 0; fc < 4; ++fc) {
                const short8 kf0 = *(const short8*)&ktb[fOff[fc][0]];
                const short8 kf1 = *(const short8*)&ktb[fOff[fc][1]];
                floatx4 tacc = (floatx4){0.f, 0.f, 0.f, 0.f};
                __builtin_amdgcn_s_setprio(1);
                tacc = __builtin_amdgcn_mfma_f32_16x16x32_bf16(kf0, qf[0], tacc, 0, 0, 0);
                tacc = __builtin_amdgcn_mfma_f32_16x16x32_bf16(kf1, qf[1], tacc, 0, 0, 0);
                __builtin_amdgcn_s_setprio(0);
                s[fc] = tacc;
            }
            #pragma unroll
            for (int fc = 0; fc < 4; ++fc)
                #pragma unroll
                for (int r = 0; r < 4; ++r) {
                    const float p = __builtin_amdgcn_exp2f(s[fc][r] + aqs * akv[fc][r]);
                    s[fc][r] = p;
                    l_part += p;
                }

            #pragma unroll
            for (int fc = 0; fc < 4; ++fc) {
                uint2 pk;
                pk.x = cvtpk(s[fc][0], s[fc][1]);
                pk.y = cvtpk(s[fc][2], s[fc][3]);
                *(uint2*)((char*)&P2[w][0] + pwOff[fc]) = pk;
            }
            short8 pf[2];
            #pragma unroll
            for (int kk = 0; kk < 2; ++kk)
                pf[kk] = *(const short8*)((const char*)&P2[w][0] + prOff[kk]);
            #pragma unroll
            for (int fd = 0; fd < 4; ++fd) {
                const short8 vf0 = *(const short8*)&vtb[fOff[fd][0]];
                const short8 vf1 = *(const short8*)&vtb[fOff[fd][1]];
                __builtin_amdgcn_s_setprio(1);
                o[fd] = __builtin_amdgcn_mfma_f32_16x16x32_bf16(vf0, pf[0], o[fd], 0, 0, 0);
                o[fd] = __builtin_amdgcn_mfma_f32_16x16x32_bf16(vf1, pf[1], o[fd], 0, 0, 0);
                __builtin_amdgcn_s_setprio(0);
            }
        }

        __syncthreads();   // prefetch loads drained (had full compute phase) + reads done
        cur ^= 1;
    }

    l_part += __shfl_xor(l_part, 16);
    l_part += __shfl_xor(l_part, 32);
    const float inv = 1.0f / l_part;
    const size_t orow = (size_t)(b * TT + q_glob) * 512 + h * 64;
    #pragma unroll
    for (int fd = 0; fd < 4; ++fd) {
        uint2 pk;
        pk.x = cvtpk(o[fd][0] * inv, o[fd][1] * inv);
        pk.y = cvtpk(o[fd][2] * inv, o[fd][3] * inv);
        *(uint2*)&Oh[orow + fd * 16 + g * 4] = pk;
    }
}

// ---------------- launch ----------------
extern "C" void kernel_launch(void* const* d_in, const int* in_sizes, int n_in,
                              void* d_out, int out_size, void* d_ws, size_t ws_size,
                              hipStream_t stream)
{
    const float* x         = (const float*)d_in[0];
    const float* Avec      = (const float*)d_in[1];
    const float* alpha_b   = (const float*)d_in[2];
    const float* dst_alpha = (const float*)d_in[3];
    const float* dst_beta  = (const float*)d_in[4];
    const float* conv1_w   = (const float*)d_in[5];
    const float* conv1_b   = (const float*)d_in[6];
    const float* ln1_g     = (const float*)d_in[7];
    const float* ln1_b     = (const float*)d_in[8];
    const float* in_proj_w = (const float*)d_in[9];
    const float* in_proj_b = (const float*)d_in[10];
    const float* out_w     = (const float*)d_in[11];
    const float* out_b     = (const float*)d_in[12];
    const float* ln2_g     = (const float*)d_in[13];
    const float* ln2_b     = (const float*)d_in[14];
    const float* mlp_w1    = (const float*)d_in[15];
    const float* mlp_b1    = (const float*)d_in[16];
    const float* mlp_w2    = (const float*)d_in[17];
    const float* mlp_b2    = (const float*)d_in[18];
    const float* dsa_ln_g  = (const float*)d_in[19];
    const float* dsa_ln_b  = (const float*)d_in[20];
    const float* dsa_dw    = (const float*)d_in[21];
    const float* dsa_db    = (const float*)d_in[22];
    const float* dsa_pw    = (const float*)d_in[23];
    const float* dsa_pb    = (const float*)d_in[24];

    unsigned short* W    = (unsigned short*)d_ws;            // N1
    unsigned short* xpad = W + N1;                           // 4*2050*512
    unsigned short* Qb   = xpad + (size_t)4 * (TT + 2) * 512;
    unsigned short* Kbf  = Qb + N1;
    unsigned short* Vt   = Kbf + N1;
    unsigned short* Zb   = Vt + N1;
    unsigned short* Tb   = Qb;                               // [8192][2048] overlays Qb..Zb
    unsigned short* Gb   = Zb + N1;
    unsigned short* Db   = Gb + N1;
    unsigned short* U1   = Db + N1;
    unsigned short* U2   = U1 + N1;
    unsigned short* U3   = U2 + N1;

    const int off_qkv = 0, off_out = 786432, off_w1 = 1048576,
              off_w2 = 2097152, off_pw = 3145728, off_cv = 3407872;

    pack_w<<<16384, 256, 0, stream>>>(in_proj_w, out_w, mlp_w1, mlp_w2, dsa_pw, conv1_w, W);
    pack_x<<<MROWS, 256, 0, stream>>>(x, dsa_ln_g, dsa_ln_b, Zb, xpad);

    // --- DSA depthwise, then fused {dsa pointwise GEMM, conv premix GEMM} ---
    dwconv_k<<<MROWS, 256, 0, stream>>>(Zb, dsa_dw, dsa_db, Gb);
    gemm_dual<<<dim3(4, 128, 2), 256, 0, stream>>>(Gb, W + off_pw, dsa_pb, Db,
        xpad, W + off_cv, conv1_b, x, U1);
    ln_bf<<<MROWS, 256, 0, stream>>>(U1, ln1_g, ln1_b, U2);

    // --- qkv projection (q*0.125*log2e, k, v transposed) ---
    gemm_k<0, 0><<<dim3(12, 128), 256, 0, stream>>>(U2, W + off_qkv, in_proj_b,
        nullptr, nullptr, nullptr, nullptr, nullptr, Qb, Kbf, Vt, 1536, 512);

    // --- attention ---
    attn_k<<<dim3(16, 8, 4), 512, 0, stream>>>(Qb, Kbf, Vt, Avec, alpha_b, U1);

    // --- out projection + residual, LN2 ---
    gemm_k<3, 0><<<dim3(4, 128), 256, 0, stream>>>(U1, W + off_out, out_b,
        x, nullptr, nullptr, nullptr, nullptr, U3, nullptr, nullptr, 512, 512);
    ln_bf<<<MROWS, 256, 0, stream>>>(U3, ln2_g, ln2_b, U2);

    // --- MLP ---
    gemm_k<4, 0><<<dim3(16, 128), 256, 0, stream>>>(U2, W + off_w1, mlp_b1,
        nullptr, nullptr, nullptr, nullptr, nullptr, Tb, nullptr, nullptr, 2048, 512);
    gemm_k<5, 0><<<dim3(4, 128), 256, 0, stream>>>(Tb, W + off_w2, mlp_b2,
        nullptr, Db, dst_alpha, dst_beta, (float*)d_out, nullptr, nullptr, nullptr,
        512, 2048);
}

// Round 18
// 248.056 us; speedup vs baseline: 1.3844x; 1.0034x over previous
//
#include <hip/hip_runtime.h>
#include <cmath>

typedef __attribute__((ext_vector_type(8))) short short8;
typedef __attribute__((ext_vector_type(4))) float floatx4;

#define TT 2048
#define CCH 512
#define MROWS 8192
static const size_t N1 = 4194304;   // 8192*512 elements
#define LOG2E 1.44269504088896340736f

__device__ __forceinline__ float gelu_f(float x) {
    return 0.5f * x * (1.0f + erff(x * 0.70710678118654752440f));
}
__device__ __forceinline__ unsigned short f2bf(float x) {
    union { float f; unsigned u; } v; v.f = x;
    unsigned r = v.u + 0x7fffu + ((v.u >> 16) & 1u);
    return (unsigned short)(r >> 16);
}
__device__ __forceinline__ float bf2f(unsigned short h) {
    union { unsigned u; float f; } v; v.u = ((unsigned)h) << 16;
    return v.f;
}
__device__ __forceinline__ unsigned cvtpk(float a, float b) {
    unsigned r;
    asm("v_cvt_pk_bf16_f32 %0, %1, %2" : "=v"(r) : "v"(a), "v"(b));
    return r;
}
__device__ __forceinline__ void gld16(const unsigned short* g, unsigned short* l) {
    __builtin_amdgcn_global_load_lds(
        (const __attribute__((address_space(1))) void*)g,
        (__attribute__((address_space(3))) void*)l, 16, 0, 0);
}

// ---------------- weight pack: fp32 -> bf16 (conv weights re-laid-out) ----------------
__global__ __launch_bounds__(256)
void pack_w(const float* __restrict__ qkvw, const float* __restrict__ outw,
            const float* __restrict__ w1, const float* __restrict__ w2,
            const float* __restrict__ pw, const float* __restrict__ cv,
            unsigned short* __restrict__ W)
{
    const int idx = blockIdx.x * 256 + threadIdx.x;
    float v;
    if (idx < 786432)            v = qkvw[idx];
    else if (idx < 1048576)      v = outw[idx - 786432];
    else if (idx < 2097152)      v = w1[idx - 1048576];
    else if (idx < 3145728)      v = w2[idx - 2097152];
    else if (idx < 3407872)      v = pw[idx - 3145728];
    else {
        const int l = idx - 3407872;
        const int n = l / 1536, k = l - n * 1536;
        const int ks = k >> 9, ci = k & 511;
        v = cv[n * 1536 + ci * 3 + ks];
    }
    W[idx] = f2bf(v);
}

// ---------------- fused: xpad bf16 (zero-padded rows) + DSA LayerNorm ----------------
__global__ __launch_bounds__(256)
void pack_x(const float* __restrict__ x, const float* __restrict__ gam,
            const float* __restrict__ bet, unsigned short* __restrict__ z,
            unsigned short* __restrict__ xpad)
{
    const int m = blockIdx.x, tid = threadIdx.x;
    const int b = m >> 11, t = m & (TT - 1);
    const float2 xv = *(const float2*)&x[(size_t)m * 512 + 2 * tid];
    float s = xv.x + xv.y, sq = xv.x * xv.x + xv.y * xv.y;
    #pragma unroll
    for (int off = 32; off; off >>= 1) { s += __shfl_xor(s, off); sq += __shfl_xor(sq, off); }
    __shared__ float ws[4], wq[4];
    const int wave = tid >> 6, lane = tid & 63;
    if (lane == 0) { ws[wave] = s; wq[wave] = sq; }
    __syncthreads();
    s = ws[0] + ws[1] + ws[2] + ws[3];
    sq = wq[0] + wq[1] + wq[2] + wq[3];
    const float mean = s * (1.0f / 512.0f);
    const float var = sq * (1.0f / 512.0f) - mean * mean;
    const float rstd = rsqrtf(var + 1e-5f);
    const float y0 = (xv.x - mean) * rstd * gam[2 * tid]     + bet[2 * tid];
    const float y1 = (xv.y - mean) * rstd * gam[2 * tid + 1] + bet[2 * tid + 1];
    *(unsigned*)&z[(size_t)m * 512 + 2 * tid] = ((unsigned)f2bf(y1) << 16) | f2bf(y0);
    *(unsigned*)&xpad[((size_t)(b * (TT + 2) + t + 1)) * 512 + 2 * tid] =
        ((unsigned)f2bf(xv.y) << 16) | f2bf(xv.x);
    if (t == 0)
        *(unsigned*)&xpad[((size_t)(b * (TT + 2))) * 512 + 2 * tid] = 0u;
    if (t == TT - 1)
        *(unsigned*)&xpad[((size_t)(b * (TT + 2) + TT + 1)) * 512 + 2 * tid] = 0u;
}

// ---------------- LayerNorm rows of 512, bf16 -> bf16 ----------------
__global__ __launch_bounds__(256)
void ln_bf(const unsigned short* __restrict__ in, const float* __restrict__ gam,
           const float* __restrict__ bet, unsigned short* __restrict__ out)
{
    const int m = blockIdx.x, tid = threadIdx.x;
    const unsigned pv = *(const unsigned*)&in[(size_t)m * 512 + 2 * tid];
    const float x0 = bf2f((unsigned short)pv), x1 = bf2f((unsigned short)(pv >> 16));
    float s = x0 + x1, sq = x0 * x0 + x1 * x1;
    #pragma unroll
    for (int off = 32; off; off >>= 1) { s += __shfl_xor(s, off); sq += __shfl_xor(sq, off); }
    __shared__ float ws[4], wq[4];
    const int wave = tid >> 6, lane = tid & 63;
    if (lane == 0) { ws[wave] = s; wq[wave] = sq; }
    __syncthreads();
    s = ws[0] + ws[1] + ws[2] + ws[3];
    sq = wq[0] + wq[1] + wq[2] + wq[3];
    const float mean = s * (1.0f / 512.0f);
    const float var = sq * (1.0f / 512.0f) - mean * mean;
    const float rstd = rsqrtf(var + 1e-5f);
    const float y0 = (x0 - mean) * rstd * gam[2 * tid]     + bet[2 * tid];
    const float y1 = (x1 - mean) * rstd * gam[2 * tid + 1] + bet[2 * tid + 1];
    *(unsigned*)&out[(size_t)m * 512 + 2 * tid] = ((unsigned)f2bf(y1) << 16) | f2bf(y0);
}

// ---------------- depthwise conv k=3 + bias + gelu ----------------
__global__ __launch_bounds__(256)
void dwconv_k(const unsigned short* __restrict__ z, const float* __restrict__ dw,
              const float* __restrict__ db, unsigned short* __restrict__ g)
{
    const int m = blockIdx.x, tid = threadIdx.x, t = m & (TT - 1);
    const int c = 2 * tid;
    const size_t base = (size_t)m * 512 + c;
    const unsigned vm = *(const unsigned*)&z[base];
    const unsigned va = (t > 0)      ? *(const unsigned*)&z[base - 512] : 0u;
    const unsigned vc = (t < TT - 1) ? *(const unsigned*)&z[base + 512] : 0u;
    float y[2];
    #pragma unroll
    for (int j = 0; j < 2; ++j) {
        const float a  = bf2f((unsigned short)(va >> (16 * j)));
        const float bb = bf2f((unsigned short)(vm >> (16 * j)));
        const float cc = bf2f((unsigned short)(vc >> (16 * j)));
        const int ch = c + j;
        y[j] = gelu_f(a * dw[ch * 3] + bb * dw[ch * 3 + 1] + cc * dw[ch * 3 + 2] + db[ch]);
    }
    *(unsigned*)&g[base] = ((unsigned)f2bf(y[1]) << 16) | f2bf(y[0]);
}

// --- bf16 MFMA GEMM body: TM=64/TN=128, NBUF=2, 24 KB LDS (6 blocks/CU),
//     simple 2-buffer loop, bijective XCD-chunked block swizzle.
// EPI: 0=qkv-split  1=bias->bf16  2=gelu+res(f32)->bf16  3=bias+res(f32)->bf16
//      4=bias+gelu->bf16  5=final combine -> f32
// AF : 0=A plain bf16 row-major   1=A from xpad (conv premix im2col)
template<int EPI, int AF>
__device__ __forceinline__ void gemm_body(
    const unsigned short* __restrict__ A, const unsigned short* __restrict__ Bw,
    const float* __restrict__ bias, const float* __restrict__ resf,
    const unsigned short* __restrict__ dsa,
    const float* __restrict__ sA, const float* __restrict__ sB,
    float* __restrict__ outf, unsigned short* __restrict__ o1,
    unsigned short* __restrict__ o2, unsigned short* __restrict__ o3,
    int Nn, int K, int gx, unsigned short* AsB, unsigned short* BsB)
{
    constexpr int MI = 4, NJ = 2;
    constexpr int ASTR = 64 * 32, BSTR = 128 * 32;

    const int nwg = gx * gridDim.y;
    const int orig = blockIdx.x + gx * blockIdx.y;
    const int wg = (orig & 7) * (nwg >> 3) + (orig >> 3);
    const int bx = wg % gx, by = wg / gx;

    const int tid = threadIdx.x;
    const int bm = by * 64, bn = bx * 128;
    const int lane = tid & 63, w = tid >> 6;
    const int wc = w;
    const int lr = lane & 15, g = lane >> 4;

    auto stage = [&](int buf, int k0) {
        unsigned short* Asb = AsB + buf * ASTR;
        unsigned short* Bsb = BsB + buf * BSTR;
        {
            const int c = tid;
            const int r = c >> 2, c8 = c & 3;
            const int c8s = c8 ^ ((r >> 1) & 3);
            const unsigned short* src;
            if (AF == 1) {
                const int m = bm + r;
                const int b = m >> 11, t = m & (TT - 1);
                const int k = k0 + c8s * 8;
                const int ks = k >> 9, ci = k & 511;
                src = A + ((size_t)(b * (TT + 2) + t + ks) * 512 + ci);
            } else {
                src = A + ((size_t)(bm + r) * K + k0 + c8s * 8);
            }
            gld16(src, Asb + (size_t)c * 8);
        }
        #pragma unroll
        for (int i = 0; i < 2; ++i) {
            const int c = tid + i * 256;
            const int r = c >> 2, c8 = c & 3;
            const int c8s = c8 ^ ((r >> 1) & 3);
            gld16(Bw + ((size_t)(bn + r) * K + k0 + c8s * 8), Bsb + (size_t)c * 8);
        }
    };

    floatx4 acc[MI][NJ];
    #pragma unroll
    for (int mi = 0; mi < MI; ++mi)
        #pragma unroll
        for (int nj = 0; nj < NJ; ++nj)
            acc[mi][nj] = (floatx4){0.f, 0.f, 0.f, 0.f};

    const int nt = K >> 5;
    stage(0, 0);
    __syncthreads();
    int cur = 0;
    for (int t = 0; t < nt; ++t) {
        if (t + 1 < nt) stage(cur ^ 1, (t + 1) * 32);

        const unsigned short* Asb = AsB + cur * ASTR;
        const unsigned short* Bsb = BsB + cur * BSTR;
        short8 av[MI], bv[NJ];
        #pragma unroll
        for (int mi = 0; mi < MI; ++mi) {
            const int row = mi * 16 + lr;
            av[mi] = *(const short8*)&Asb[row * 32 + (g ^ ((row >> 1) & 3)) * 8];
        }
        #pragma unroll
        for (int nj = 0; nj < NJ; ++nj) {
            const int row = wc * 32 + nj * 16 + lr;
            bv[nj] = *(const short8*)&Bsb[row * 32 + (g ^ ((row >> 1) & 3)) * 8];
        }
        __builtin_amdgcn_s_setprio(1);
        #pragma unroll
        for (int mi = 0; mi < MI; ++mi)
            #pragma unroll
            for (int nj = 0; nj < NJ; ++nj)
                acc[mi][nj] = __builtin_amdgcn_mfma_f32_16x16x32_bf16(av[mi], bv[nj], acc[mi][nj], 0, 0, 0);
        __builtin_amdgcn_s_setprio(0);
        __syncthreads();
        cur ^= 1;
    }

    float sa = 0.f, sb = 0.f;
    if (EPI == 5) { sa = sA[0]; sb = sB[0]; }
    #pragma unroll
    for (int mi = 0; mi < MI; ++mi)
        #pragma unroll
        for (int nj = 0; nj < NJ; ++nj)
            #pragma unroll
            for (int reg = 0; reg < 4; ++reg) {
                const int m = bm + mi * 16 + g * 4 + reg;
                const int n = bn + wc * 32 + nj * 16 + lr;
                float v = acc[mi][nj][reg] + bias[n];
                if (EPI == 0) {
                    const int b = m >> 11, t = m & (TT - 1);
                    if (n < 512) {
                        o1[(size_t)m * 512 + n] = f2bf(v * (0.125f * LOG2E));
                    } else if (n < 1024) {
                        o2[(size_t)m * 512 + (n - 512)] = f2bf(v);
                    } else {
                        const int c = n - 1024;
                        o3[(size_t)(b * 8 + (c >> 6)) * 64 * TT + (size_t)(c & 63) * TT + t] = f2bf(v);
                    }
                } else if (EPI == 1) {
                    o1[(size_t)m * 512 + n] = f2bf(v);
                } else if (EPI == 2) {
                    o1[(size_t)m * 512 + n] = f2bf(resf[(size_t)m * 512 + n] + gelu_f(v));
                } else if (EPI == 3) {
                    o1[(size_t)m * 512 + n] = f2bf(v + resf[(size_t)m * 512 + n]);
                } else if (EPI == 4) {
                    o1[(size_t)m * Nn + n] = f2bf(gelu_f(v));
                } else {
                    outf[(size_t)m * 512 + n] = sa * v + sb * bf2f(dsa[(size_t)m * 512 + n]);
                }
            }
}

template<int EPI, int AF>
__global__ __launch_bounds__(256, 4)
void gemm_k(const unsigned short* __restrict__ A, const unsigned short* __restrict__ Bw,
            const float* __restrict__ bias, const float* __restrict__ resf,
            const unsigned short* __restrict__ dsa,
            const float* __restrict__ sA, const float* __restrict__ sB,
            float* __restrict__ outf, unsigned short* __restrict__ o1,
            unsigned short* __restrict__ o2, unsigned short* __restrict__ o3,
            int Nn, int K)
{
    __shared__ unsigned short As[2 * 64 * 32];
    __shared__ unsigned short Bs[2 * 128 * 32];
    gemm_body<EPI, AF>(A, Bw, bias, resf, dsa, sA, sB, outf, o1, o2, o3,
                       Nn, K, gridDim.x, As, Bs);
}

// fused: z=0 -> dsa pointwise GEMM (K=512); z=1 -> conv premix (K=1536, im2col)
__global__ __launch_bounds__(256, 4)
void gemm_dual(const unsigned short* __restrict__ Gb, const unsigned short* __restrict__ Wpw,
               const float* __restrict__ dsa_pb, unsigned short* __restrict__ Db,
               const unsigned short* __restrict__ xpad, const unsigned short* __restrict__ Wcv,
               const float* __restrict__ conv1_b, const float* __restrict__ x,
               unsigned short* __restrict__ U1)
{
    __shared__ unsigned short As[2 * 64 * 32];
    __shared__ unsigned short Bs[2 * 128 * 32];
    if (blockIdx.z == 0)
        gemm_body<1, 0>(Gb, Wpw, dsa_pb, nullptr, nullptr, nullptr, nullptr,
                        nullptr, Db, nullptr, nullptr, 512, 512, gridDim.x, As, Bs);
    else
        gemm_body<2, 1>(xpad, Wcv, conv1_b, x, nullptr, nullptr, nullptr,
                        nullptr, U1, nullptr, nullptr, 512, 1536, gridDim.x, As, Bs);
}

// ---- MFMA flash attention, swapped S^T = mfma(K,Q): 8 waves, QBLK=128, KVBLK=128 ----
// K/V staged via global_load_lds (pre-swizzled source, linear dest). A-vector loads
// hoisted ABOVE the prefetch so vmcnt waits on them do NOT drain the K/V prefetch
// (FIFO vmcnt: waiting on older loads leaves newer ones in flight).
__global__ __launch_bounds__(512, 2)
void attn_k(const unsigned short* __restrict__ Qb, const unsigned short* __restrict__ Kb,
            const unsigned short* __restrict__ Vtg, const float* __restrict__ Avec,
            const float* __restrict__ alpha_p, unsigned short* __restrict__ Oh)
{
    __shared__ unsigned short Kt[2][2][64 * 64];   // [buf][sub] 32 KB, swizzled layout
    __shared__ unsigned short Vt[2][2][64 * 64];   // 32 KB (V^T: rows=d, cols=key)
    __shared__ unsigned short P2[8][16 * 64];      // 16 KB (per-wave P^T spill)

    const int tid = threadIdx.x;
    const int w = tid >> 6, lane = tid & 63;
    const int lr = lane & 15, g = lane >> 4;
    const int i0 = blockIdx.x * 128;
    const int h = blockIdx.y, b = blockIdx.z;
    const float* Ab = Avec + b * TT;
    const int q_glob = i0 + w * 16 + lr;
    const float aqs = alpha_p[0] * LOG2E * Ab[q_glob];

    // ---- hoisted loop-invariant offsets ----
    int fOff[4][2];
    #pragma unroll
    for (int f = 0; f < 4; ++f) {
        const int row = f * 16 + lr;
        #pragma unroll
        for (int kk = 0; kk < 2; ++kk)
            fOff[f][kk] = row * 64 + (((kk * 64 + g * 16) ^ ((row & 7) << 4)) >> 1);
    }
    int pwOff[4], prOff[2];
    #pragma unroll
    for (int fc = 0; fc < 4; ++fc)
        pwOff[fc] = (lr * 128 + fc * 32 + g * 8) ^ ((lr & 7) << 4);
    #pragma unroll
    for (int kk = 0; kk < 2; ++kk)
        prOff[kk] = (lr * 128 + kk * 64 + g * 16) ^ ((lr & 7) << 4);

    // staging: 512 threads; row j_s, 16B chunk c8_s; linear LDS dest, swizzled SOURCE
    const int j_s = tid >> 3, c8_s = tid & 7;
    const int c8sw = c8_s ^ (j_s & 7);
    const int dOff = j_s * 64 + c8_s * 8;

    const unsigned short* kBase = Kb + (size_t)(b * TT + j_s) * 512 + h * 64 + c8sw * 8;
    const unsigned short* vBase = Vtg + (size_t)((b * 8 + h) * 64 + j_s) * TT + c8sw * 8;

    auto stage = [&](int buf, int kv0) {
        #pragma unroll
        for (int i = 0; i < 2; ++i) {
            gld16(kBase + (size_t)(kv0 + i * 64) * 512, &Kt[buf][i][dOff]);
            gld16(vBase + kv0 + i * 64, &Vt[buf][i][dOff]);
        }
    };

    const float* aP = Ab + g * 4;

    short8 qf[2];
    #pragma unroll
    for (int kk = 0; kk < 2; ++kk)
        qf[kk] = *(const short8*)&Qb[(size_t)(b * TT + q_glob) * 512 + h * 64 + kk * 32 + g * 8];

    float l_part = 0.f;
    floatx4 o[4];
    #pragma unroll
    for (int fd = 0; fd < 4; ++fd) o[fd] = (floatx4){0.f, 0.f, 0.f, 0.f};

    stage(0, 0);
    __syncthreads();
    int cur = 0;

    for (int t = 0; t < 16; ++t) {
        // A-vectors for BOTH subtiles: issued BEFORE the prefetch (older in VMEM FIFO)
        floatx4 akv[2][4];
        #pragma unroll
        for (int st = 0; st < 2; ++st)
            #pragma unroll
            for (int fc = 0; fc < 4; ++fc)
                akv[st][fc] = *(const floatx4*)(aP + st * 64 + fc * 16);
        aP += 128;

        if (t < 15) stage(cur ^ 1, (t + 1) * 128);   // prefetch stays in flight all phase

        #pragma unroll
        for (int st = 0; st < 2; ++st) {
            const unsigned short* ktb = &Kt[cur][st][0];
            const unsigned short* vtb = &Vt[cur][st][0];

            floatx4 s[4];
            #pragma unroll
            for (int fc = 0; fc < 4; ++fc) {
                const short8 kf0 = *(const short8*)&ktb[fOff[fc][0]];
                const short8 kf1 = *(const short8*)&ktb[fOff[fc][1]];
                floatx4 tacc = (floatx4){0.f, 0.f, 0.f, 0.f};
                __builtin_amdgcn_s_setprio(1);
                tacc = __builtin_amdgcn_mfma_f32_16x16x32_bf16(kf0, qf[0], tacc, 0, 0, 0);
                tacc = __builtin_amdgcn_mfma_f32_16x16x32_bf16(kf1, qf[1], tacc, 0, 0, 0);
                __builtin_amdgcn_s_setprio(0);
                s[fc] = tacc;
            }
            #pragma unroll
            for (int fc = 0; fc < 4; ++fc)
                #pragma unroll
                for (int r = 0; r < 4; ++r) {
                    const float p = __builtin_amdgcn_exp2f(s[fc][r] + aqs * akv[st][fc][r]);
                    s[fc][r] = p;
                    l_part += p;
                }

            #pragma unroll
            for (int fc = 0; fc < 4; ++fc) {
                uint2 pk;
                pk.x = cvtpk(s[fc][0], s[fc][1]);
                pk.y = cvtpk(s[fc][2], s[fc][3]);
                *(uint2*)((char*)&P2[w][0] + pwOff[fc]) = pk;
            }
            short8 pf[2];
            #pragma unroll
            for (int kk = 0; kk < 2; ++kk)
                pf[kk] = *(const short8*)((const char*)&P2[w][0] + prOff[kk]);
            #pragma unroll
            for (int fd = 0; fd < 4; ++fd) {
                const short8 vf0 = *(const short8*)&vtb[fOff[fd][0]];
                const short8 vf1 = *(const short8*)&vtb[fOff[fd][1]];
                __builtin_amdgcn_s_setprio(1);
                o[fd] = __builtin_amdgcn_mfma_f32_16x16x32_bf16(vf0, pf[0], o[fd], 0, 0, 0);
                o[fd] = __builtin_amdgcn_mfma_f32_16x16x32_bf16(vf1, pf[1], o[fd], 0, 0, 0);
                __builtin_amdgcn_s_setprio(0);
            }
        }

        __syncthreads();   // prefetch loads drained (spanned full compute phase)
        cur ^= 1;
    }

    l_part += __shfl_xor(l_part, 16);
    l_part += __shfl_xor(l_part, 32);
    const float inv = 1.0f / l_part;
    const size_t orow = (size_t)(b * TT + q_glob) * 512 + h * 64;
    #pragma unroll
    for (int fd = 0; fd < 4; ++fd) {
        uint2 pk;
        pk.x = cvtpk(o[fd][0] * inv, o[fd][1] * inv);
        pk.y = cvtpk(o[fd][2] * inv, o[fd][3] * inv);
        *(uint2*)&Oh[orow + fd * 16 + g * 4] = pk;
    }
}

// ---------------- launch ----------------
extern "C" void kernel_launch(void* const* d_in, const int* in_sizes, int n_in,
                              void* d_out, int out_size, void* d_ws, size_t ws_size,
                              hipStream_t stream)
{
    const float* x         = (const float*)d_in[0];
    const float* Avec      = (const float*)d_in[1];
    const float* alpha_b   = (const float*)d_in[2];
    const float* dst_alpha = (const float*)d_in[3];
    const float* dst_beta  = (const float*)d_in[4];
    const float* conv1_w   = (const float*)d_in[5];
    const float* conv1_b   = (const float*)d_in[6];
    const float* ln1_g     = (const float*)d_in[7];
    const float* ln1_b     = (const float*)d_in[8];
    const float* in_proj_w = (const float*)d_in[9];
    const float* in_proj_b = (const float*)d_in[10];
    const float* out_w     = (const float*)d_in[11];
    const float* out_b     = (const float*)d_in[12];
    const float* ln2_g     = (const float*)d_in[13];
    const float* ln2_b     = (const float*)d_in[14];
    const float* mlp_w1    = (const float*)d_in[15];
    const float* mlp_b1    = (const float*)d_in[16];
    const float* mlp_w2    = (const float*)d_in[17];
    const float* mlp_b2    = (const float*)d_in[18];
    const float* dsa_ln_g  = (const float*)d_in[19];
    const float* dsa_ln_b  = (const float*)d_in[20];
    const float* dsa_dw    = (const float*)d_in[21];
    const float* dsa_db    = (const float*)d_in[22];
    const float* dsa_pw    = (const float*)d_in[23];
    const float* dsa_pb    = (const float*)d_in[24];

    unsigned short* W    = (unsigned short*)d_ws;            // N1
    unsigned short* xpad = W + N1;                           // 4*2050*512
    unsigned short* Qb   = xpad + (size_t)4 * (TT + 2) * 512;
    unsigned short* Kbf  = Qb + N1;
    unsigned short* Vt   = Kbf + N1;
    unsigned short* Zb   = Vt + N1;
    unsigned short* Tb   = Qb;                               // [8192][2048] overlays Qb..Zb
    unsigned short* Gb   = Zb + N1;
    unsigned short* Db   = Gb + N1;
    unsigned short* U1   = Db + N1;
    unsigned short* U2   = U1 + N1;
    unsigned short* U3   = U2 + N1;

    const int off_qkv = 0, off_out = 786432, off_w1 = 1048576,
              off_w2 = 2097152, off_pw = 3145728, off_cv = 3407872;

    pack_w<<<16384, 256, 0, stream>>>(in_proj_w, out_w, mlp_w1, mlp_w2, dsa_pw, conv1_w, W);
    pack_x<<<MROWS, 256, 0, stream>>>(x, dsa_ln_g, dsa_ln_b, Zb, xpad);

    // --- DSA depthwise, then fused {dsa pointwise GEMM, conv premix GEMM} ---
    dwconv_k<<<MROWS, 256, 0, stream>>>(Zb, dsa_dw, dsa_db, Gb);
    gemm_dual<<<dim3(4, 128, 2), 256, 0, stream>>>(Gb, W + off_pw, dsa_pb, Db,
        xpad, W + off_cv, conv1_b, x, U1);
    ln_bf<<<MROWS, 256, 0, stream>>>(U1, ln1_g, ln1_b, U2);

    // --- qkv projection (q*0.125*log2e, k, v transposed) ---
    gemm_k<0, 0><<<dim3(12, 128), 256, 0, stream>>>(U2, W + off_qkv, in_proj_b,
        nullptr, nullptr, nullptr, nullptr, nullptr, Qb, Kbf, Vt, 1536, 512);

    // --- attention ---
    attn_k<<<dim3(16, 8, 4), 512, 0, stream>>>(Qb, Kbf, Vt, Avec, alpha_b, U1);

    // --- out projection + residual, LN2 ---
    gemm_k<3, 0><<<dim3(4, 128), 256, 0, stream>>>(U1, W + off_out, out_b,
        x, nullptr, nullptr, nullptr, nullptr, U3, nullptr, nullptr, 512, 512);
    ln_bf<<<MROWS, 256, 0, stream>>>(U3, ln2_g, ln2_b, U2);

    // --- MLP ---
    gemm_k<4, 0><<<dim3(16, 128), 256, 0, stream>>>(U2, W + off_w1, mlp_b1,
        nullptr, nullptr, nullptr, nullptr, nullptr, Tb, nullptr, nullptr, 2048, 512);
    gemm_k<5, 0><<<dim3(4, 128), 256, 0, stream>>>(Tb, W + off_w2, mlp_b2,
        nullptr, Db, dst_alpha, dst_beta, (float*)d_out, nullptr, nullptr, nullptr,
        512, 2048);
}